// Round 9
// baseline (532.257 us; speedup 1.0000x reference)
//
#include <hip/hip_runtime.h>
#include <hip/hip_fp16.h>

#define N_NODES 50000
#define N_EDGES 800000
#define SLOPE 0.15f

typedef unsigned short u16;
typedef __attribute__((ext_vector_type(8))) _Float16 f16x8;
typedef __attribute__((ext_vector_type(2))) _Float16 h16x2;
typedef __attribute__((ext_vector_type(4))) float f32x4;

static __device__ __forceinline__ float leaky(float v) { return v > 0.f ? v : SLOPE * v; }

static __device__ __forceinline__ u16 f2h(float v) {
    return __builtin_bit_cast(u16, __float2half(v));
}

// acc += lo_half + hi_half of u (fp16 pair), f32 accumulate via v_dot2_f32_f16
static __device__ __forceinline__ float dot2acc(unsigned int u, float c) {
    h16x2 one = {(_Float16)1.0f, (_Float16)1.0f};
    return __builtin_amdgcn_fdot2(__builtin_bit_cast(h16x2, u), one, c, false);
}

// async global->LDS 16B: HW writes lane's data to (wave-uniform lds base) + lane*16
static __device__ __forceinline__ void async_load16(const u16* g, u16* l) {
    __builtin_amdgcn_global_load_lds(
        (const __attribute__((address_space(1))) unsigned int*)g,
        (__attribute__((address_space(3))) unsigned int*)l, 16, 0, 0);
}

// ---------------- merged prep: edge count+rank | x->fp16 | weight transpose | padzero
// block ranges: [0,3125) count+rank; [3125,9375) xconv; [9375,11039) wconv; [11039,11041) pad
__global__ void k_prep(const int* __restrict__ dst, int* __restrict__ cnt,
                       int* __restrict__ erank,
                       const float* __restrict__ x, u16* __restrict__ xp,
                       const float* __restrict__ W1l, const float* __restrict__ W1r,
                       const float* __restrict__ W2l, const float* __restrict__ W2r,
                       const float* __restrict__ W3l, const float* __restrict__ W3r,
                       u16* w1lp, u16* w1rp, u16* w2cp, u16* w3cp,
                       u16* z2h, u16* z3h) {
    int b = blockIdx.x, tid = threadIdx.x;
    if (b < 3125) {
        int e = b * 256 + tid;
        if (e < N_EDGES) erank[e] = atomicAdd(&cnt[dst[e]], 1);  // rank within dst node
        return;
    }
    b -= 3125;
    if (b < 6250) {
        int i = b * 256 + tid;
        if (i >= N_NODES * 32) return;
        float4 v = ((const float4*)x)[i];
        ((ushort4*)xp)[i] = make_ushort4(f2h(v.x), f2h(v.y), f2h(v.z), f2h(v.w));
        return;
    }
    b -= 6250;
    if (b >= 1664) {   // pad-row zeroing: xp row N (128), z2h row N (256), z3h row N (64)
        int i = (b - 1664) * 256 + tid;
        if (i < 128)      xp[(size_t)N_NODES * 128 + i] = 0;
        else if (i < 384) z2h[(size_t)N_NODES * 256 + (i - 128)] = 0;
        else if (i < 448) z3h[(size_t)N_NODES * 64 + (i - 384)] = 0;
        return;
    }
    const float* W; u16* op; int K, N;
    if (b < 256)       { W = W1l; op = w1lp; K = 128; N = 512; }
    else if (b < 512)  { W = W1r; op = w1rp; K = 128; N = 512; b -= 256; }
    else if (b < 1024) { W = W2l; op = w2cp; K = 512; N = 256; b -= 512; }
    else if (b < 1536) { W = W2r; op = w2cp + 256 * 512; K = 512; N = 256; b -= 1024; }
    else if (b < 1600) { W = W3l; op = w3cp; K = 256; N = 64; b -= 1536; }
    else               { W = W3r; op = w3cp + 64 * 256; K = 256; N = 64; b -= 1600; }
    int i = b * 256 + tid;
    if (i >= K * N) return;
    int k = i / N, n = i - k * N;
    op[(size_t)n * K + k] = f2h(W[i]);   // W^T [N][K] fp16
}

// multi-block scan over PADDED counts (pad each node to multiple of 16 slots)
__global__ __launch_bounds__(1024) void k_scan1(const int* __restrict__ cnt,
                                                int* __restrict__ offs,
                                                int* __restrict__ bsum) {
    __shared__ int wsum[16];
    int tid = threadIdx.x, lane = tid & 63, wv = tid >> 6;
    int i = blockIdx.x * 1024 + tid;
    int c = (i < N_NODES) ? cnt[i] : 0;
    int orig = (c + 15) & ~15;          // padded count
    int v = orig;
#pragma unroll
    for (int d = 1; d < 64; d <<= 1) {
        int t = __shfl_up(v, d, 64);
        if (lane >= d) v += t;
    }
    if (lane == 63) wsum[wv] = v;
    __syncthreads();
    if (wv == 0) {
        int s = (lane < 16) ? wsum[lane] : 0;
#pragma unroll
        for (int d = 1; d < 16; d <<= 1) {
            int t = __shfl_up(s, d, 64);
            if (lane >= d) s += t;
        }
        if (lane < 16) wsum[lane] = s;
        if (lane == 15) bsum[blockIdx.x] = s;
    }
    __syncthreads();
    int wpre = (wv == 0) ? 0 : wsum[wv - 1];
    if (i < N_NODES) offs[i] = v + wpre - orig;
}

// stage 2+3 merged (padded offsets; offs[N_NODES]=total) + per-node pad-sentinel fill
__global__ void k_scan3(const int* __restrict__ cnt, int* __restrict__ offs,
                        float* __restrict__ inv, int* __restrict__ pssrc,
                        const int* __restrict__ bsum, int nb) {
    __shared__ int sb[64];
    int tid = threadIdx.x;
    if (tid < 64) {
        int v = (tid < nb) ? bsum[tid] : 0;
        int s = v;
#pragma unroll
        for (int d = 1; d < 64; d <<= 1) {
            int t = __shfl_up(s, d, 64);
            if (tid >= d) s += t;
        }
        sb[tid] = s - v;
        if (blockIdx.x == 0 && tid == nb - 1) offs[N_NODES] = s;  // total padded
    }
    __syncthreads();
    int i = blockIdx.x * 256 + tid;
    if (i >= N_NODES) return;
    int c = cnt[i];
    int o = offs[i] + sb[i >> 10];
    offs[i] = o;
    inv[i] = 1.0f / (float)(c > 1 ? c : 1);
    int cp = (c + 15) & ~15;
    for (int j = c; j < cp; ++j) pssrc[o + j] = N_NODES;   // zero pad row sentinel
}

// atomic-free fill: pssrc[offs[dst]+rank] = src ; 4 edges/thread, fire-and-forget
__global__ void k_fill(const int* __restrict__ src, const int* __restrict__ dst,
                       const int* __restrict__ erank, const int* __restrict__ poffs,
                       int* __restrict__ pssrc) {
    int t = blockIdx.x * 256 + threadIdx.x;
    int e = t * 4;
    if (e + 3 >= N_EDGES) {
        for (; e < N_EDGES; ++e) pssrc[poffs[dst[e]] + erank[e]] = src[e];
        return;
    }
    int4 d4 = *(const int4*)&dst[e];
    int4 s4 = *(const int4*)&src[e];
    int4 r4 = *(const int4*)&erank[e];
    int p0 = poffs[d4.x] + r4.x;
    int p1 = poffs[d4.y] + r4.y;
    int p2 = poffs[d4.z] + r4.z;
    int p3 = poffs[d4.w] + r4.w;
    pssrc[p0] = s4.x;
    pssrc[p1] = s4.y;
    pssrc[p2] = s4.z;
    pssrc[p3] = s4.w;
}

// ---------------- padded-CSR mean aggregation, full-row waves --------------------
// EPI: 0 = mean -> fp16 outh; 2 = leaky(mean+y+bias) -> fp16 outh
template <int STRIDE, int EPI, int LPE, int U>
__global__ __launch_bounds__(256) void k_agg(const u16* __restrict__ tbl,
                                             const int* __restrict__ poffs,
                                             const int* __restrict__ pssrc,
                                             const float* __restrict__ inv,
                                             const u16* __restrict__ y,
                                             const float* __restrict__ bias,
                                             u16* __restrict__ outh) {
    constexpr int G = 64 / LPE;
    int wid = (blockIdx.x * 256 + threadIdx.x) >> 6;
    if (wid >= N_NODES) return;
    int lane = threadIdx.x & 63;
    int g = lane / LPE;
    int cl = lane % LPE;
    int beg = poffs[wid], end = poffs[wid + 1];
    const u16* colbase = tbl + cl * 8;
    float acc[8] = {};
    for (int e = beg + g * U; e < end; e += G * U) {
        int idx[U];
        if constexpr (U == 4) {
            int4 t4 = *(const int4*)&pssrc[e];
            idx[0] = t4.x; idx[1] = t4.y; idx[2] = t4.z; idx[3] = t4.w;
        } else {
            int2 t2 = *(const int2*)&pssrc[e];
            idx[0] = t2.x; idx[1] = t2.y;
        }
        uint4 rv[U];
#pragma unroll
        for (int j = 0; j < U; ++j)
            rv[j] = *(const uint4*)(colbase + (size_t)idx[j] * STRIDE);
#pragma unroll
        for (int p = 0; p < U / 2; ++p) {
            const unsigned int* a = (const unsigned int*)&rv[2 * p];
            const unsigned int* b = (const unsigned int*)&rv[2 * p + 1];
#pragma unroll
            for (int t = 0; t < 4; ++t) {
                unsigned int lo = __builtin_amdgcn_perm(b[t], a[t], 0x05040100u);
                unsigned int hi = __builtin_amdgcn_perm(b[t], a[t], 0x07060302u);
                acc[2 * t + 0] = dot2acc(lo, acc[2 * t + 0]);
                acc[2 * t + 1] = dot2acc(hi, acc[2 * t + 1]);
            }
        }
    }
#pragma unroll
    for (int m = LPE; m < 64; m <<= 1)
#pragma unroll
        for (int t = 0; t < 8; ++t) acc[t] += __shfl_xor(acc[t], m, 64);
    if (g != 0) return;
    float wv = inv[wid];
    const size_t ob = (size_t)wid * STRIDE + cl * 8;
    float v[8];
    if constexpr (EPI == 0) {
#pragma unroll
        for (int t = 0; t < 8; ++t) v[t] = acc[t] * wv;
    } else {
        uint4 yv4 = *(const uint4*)(y + ob);
        const __half2* yp = (const __half2*)&yv4;
        float4 b0 = *(const float4*)(bias + cl * 8);
        float4 b1 = *(const float4*)(bias + cl * 8 + 4);
        float bb[8] = {b0.x, b0.y, b0.z, b0.w, b1.x, b1.y, b1.z, b1.w};
#pragma unroll
        for (int t = 0; t < 4; ++t) {
            float2 f = __half22float2(yp[t]);
            v[t * 2 + 0] = leaky(acc[t * 2 + 0] * wv + f.x + bb[t * 2 + 0]);
            v[t * 2 + 1] = leaky(acc[t * 2 + 1] * wv + f.y + bb[t * 2 + 1]);
        }
    }
    *(ushort4*)(outh + ob)     = make_ushort4(f2h(v[0]), f2h(v[1]), f2h(v[2]), f2h(v[3]));
    *(ushort4*)(outh + ob + 4) = make_ushort4(f2h(v[4]), f2h(v[5]), f2h(v[6]), f2h(v[7]));
}

// ---------------- layer-3 agg + FUSED HEAD: h3 -> pre_fc -> leaky(fc1) -> fc2 ------
// STRIDE=64, LPE=8, U=2. After the mean+leaky, the 8 lanes holding a node's 64-wide
// h3 row compute the 3-layer head in-register via 8-lane butterflies (weights in LDS).
// Kills the k_head dispatch and the 25.6 MB h3f round trip.
__global__ __launch_bounds__(256) void k_agg_head(
    const u16* __restrict__ tbl, const int* __restrict__ poffs,
    const int* __restrict__ pssrc, const float* __restrict__ inv,
    const u16* __restrict__ y, const float* __restrict__ bias,
    const float* __restrict__ Wp, const float* __restrict__ bp,
    const float* __restrict__ Wf1, const float* __restrict__ bf1,
    const float* __restrict__ Wf2, const float* __restrict__ bf2,
    float* __restrict__ out) {
    constexpr int LPE = 8, U = 2, G = 8, STRIDE = 64;
    __shared__ float sWp[64 * 32], sW1[32 * 32], sW2[64];
    __shared__ float sbp[32], sb1[32], sb2[2];
    int tid = threadIdx.x;
    for (int i = tid; i < 64 * 32; i += 256) sWp[i] = Wp[i];
    for (int i = tid; i < 32 * 32; i += 256) sW1[i] = Wf1[i];
    if (tid < 64) sW2[tid] = Wf2[tid];
    if (tid < 32) { sbp[tid] = bp[tid]; sb1[tid] = bf1[tid]; }
    if (tid < 2) sb2[tid] = bf2[tid];
    __syncthreads();                 // grid is exact (12500*4 waves = 50000 nodes)
    int wid = (blockIdx.x * 256 + tid) >> 6;
    int lane = tid & 63;
    int g = lane / LPE;
    int cl = lane % LPE;
    int beg = poffs[wid], end = poffs[wid + 1];
    const u16* colbase = tbl + cl * 8;
    float acc[8] = {};
    for (int e = beg + g * U; e < end; e += G * U) {
        int2 t2 = *(const int2*)&pssrc[e];
        uint4 rv0 = *(const uint4*)(colbase + (size_t)t2.x * STRIDE);
        uint4 rv1 = *(const uint4*)(colbase + (size_t)t2.y * STRIDE);
        const unsigned int* a = (const unsigned int*)&rv0;
        const unsigned int* b = (const unsigned int*)&rv1;
#pragma unroll
        for (int t = 0; t < 4; ++t) {
            unsigned int lo = __builtin_amdgcn_perm(b[t], a[t], 0x05040100u);
            unsigned int hi = __builtin_amdgcn_perm(b[t], a[t], 0x07060302u);
            acc[2 * t + 0] = dot2acc(lo, acc[2 * t + 0]);
            acc[2 * t + 1] = dot2acc(hi, acc[2 * t + 1]);
        }
    }
#pragma unroll
    for (int m = LPE; m < 64; m <<= 1)
#pragma unroll
        for (int t = 0; t < 8; ++t) acc[t] += __shfl_xor(acc[t], m, 64);
    if (g != 0) return;
    // h3 row elements i = cl*8+t  (f32, no store)
    float wv = inv[wid];
    const size_t ob = (size_t)wid * STRIDE + cl * 8;
    uint4 yv4 = *(const uint4*)(y + ob);
    const __half2* yp = (const __half2*)&yv4;
    float4 b0 = *(const float4*)(bias + cl * 8);
    float4 b1 = *(const float4*)(bias + cl * 8 + 4);
    float bb[8] = {b0.x, b0.y, b0.z, b0.w, b1.x, b1.y, b1.z, b1.w};
    float v[8];
#pragma unroll
    for (int t = 0; t < 4; ++t) {
        float2 f = __half22float2(yp[t]);
        v[t * 2 + 0] = leaky(acc[t * 2 + 0] * wv + f.x + bb[t * 2 + 0]);
        v[t * 2 + 1] = leaky(acc[t * 2 + 1] * wv + f.y + bb[t * 2 + 1]);
    }
    // pre_fc: h4[o] = bp[o] + sum_i h3[i]*Wp[i][o]; lane cl holds i = cl*8..cl*8+7
    float p[32];
#pragma unroll
    for (int o = 0; o < 32; ++o) p[o] = 0.f;
#pragma unroll
    for (int t = 0; t < 8; ++t) {
        const float* wr = &sWp[(cl * 8 + t) * 32];
        float vt = v[t];
#pragma unroll
        for (int o = 0; o < 32; ++o) p[o] += vt * wr[o];
    }
#pragma unroll
    for (int m = 1; m < 8; m <<= 1)
#pragma unroll
        for (int o = 0; o < 32; ++o) p[o] += __shfl_xor(p[o], m, 64);
#pragma unroll
    for (int o = 0; o < 32; ++o) p[o] += sbp[o];   // all 8 lanes hold full h4
    // fc1: lane cl computes outputs o = cl*4..cl*4+3
    float h5[4];
#pragma unroll
    for (int oo = 0; oo < 4; ++oo) {
        int o = cl * 4 + oo;
        float s = sb1[o];
#pragma unroll
        for (int i = 0; i < 32; ++i) s += p[i] * sW1[i * 32 + o];
        h5[oo] = leaky(s);
    }
    // fc2: partial over this lane's 4 h5 entries, butterfly over 8 lanes
    float o0 = 0.f, o1 = 0.f;
#pragma unroll
    for (int oo = 0; oo < 4; ++oo) {
        int i = cl * 4 + oo;
        o0 += h5[oo] * sW2[i * 2 + 0];
        o1 += h5[oo] * sW2[i * 2 + 1];
    }
#pragma unroll
    for (int m = 1; m < 8; m <<= 1) {
        o0 += __shfl_xor(o0, m, 64);
        o1 += __shfl_xor(o1, m, 64);
    }
    if (cl == 0) *(float2*)(out + (size_t)wid * 2) = make_float2(o0 + sb2[0], o1 + sb2[1]);
}

// ---------------- fp16 MFMA GEMM: 128x256 WIDE tile, double-buffer ----------------
// Fatter tile: per K-step stage A 8KB (shared by 2 col-halves) + B 16KB; 32 MFMA/wave.
// Halves barriers-per-output-byte and A re-reads (4x->2x) vs the 128x128 kernel.
// LDS 48KB -> 3 blocks/CU by LDS; grid halves to 784. Swapped epilogue (R8).
__global__ __launch_bounds__(256, 2) void k_gemm_w(
    int M, int nct2,
    const u16* __restrict__ A1, const u16* __restrict__ B1, int K1,
    const u16* __restrict__ A2, const u16* __restrict__ B2, int K2,
    const float* __restrict__ bias, int act, int colsplit,
    u16* __restrict__ out1h, int n1, u16* __restrict__ out2h, int n2) {
    __shared__ u16 Ash[2][4096], Bsh[2][8192];
    const int tid = threadIdx.x;
    const int lane = tid & 63;
    const int w = tid >> 6;
    const int wm = w & 1, wn = w >> 1;   // row half (64), col half (128)
    const int fr = lane & 15;
    const int q = lane >> 4;

    const int mT = (M + 127) >> 7;
    const int lin = blockIdx.x;
    const int grp = lin / (8 * nct2);
    const int idx = lin - grp * (8 * nct2);
    const int ct = idx >> 3;
    const int s8 = idx & 7;
    const int rowt = grp * 8 + s8;
    if (rowt >= mT) return;
    const int brow = rowt * 128;
    const int bcol = ct * 256;

    const int T1 = K1 >> 5, T = T1 + (K2 >> 5);

    // A staging: 8 chunks over [128][32]; 2/wave (same map as before)
    const int cA0 = (w * 2 + 0) * 64 + lane;
    const int cA1 = (w * 2 + 1) * 64 + lane;
    const int rA0 = cA0 >> 2, gA0 = (cA0 & 3) ^ ((rA0 >> 1) & 3);
    const int rA1 = cA1 >> 2, gA1 = (cA1 & 3) ^ ((rA1 >> 1) & 3);
    int ar0 = brow + rA0; if (ar0 >= M) ar0 = M - 1;
    int ar1 = brow + rA1; if (ar1 >= M) ar1 = M - 1;
    // B staging: 16 chunks over [256][32]; 4/wave
    int rB[4], gB[4];
#pragma unroll
    for (int j = 0; j < 4; ++j) {
        int s = (w * 4 + j) * 64 + lane;
        rB[j] = s >> 2;
        gB[j] = (s & 3) ^ ((rB[j] >> 1) & 3);
    }
    const int ubA0 = (w * 2 + 0) * 512;
    const int ubA1 = (w * 2 + 1) * 512;

    auto stage = [&](int kt, int buf) {
        const u16 *A, *B; int K, k0;
        if (kt < T1) { A = A1; B = B1; K = K1; k0 = kt * 32; }
        else         { A = A2; B = B2; K = K2; k0 = (kt - T1) * 32; }
        async_load16(A + (size_t)ar0 * K + k0 + gA0 * 8, &Ash[buf][ubA0]);
        async_load16(A + (size_t)ar1 * K + k0 + gA1 * 8, &Ash[buf][ubA1]);
#pragma unroll
        for (int j = 0; j < 4; ++j)
            async_load16(B + (size_t)(bcol + rB[j]) * K + k0 + gB[j] * 8,
                         &Bsh[buf][(w * 4 + j) * 512]);
    };

    f32x4 acc[4][8] = {};

    stage(0, 0);
    __syncthreads();

    int cur = 0;
    for (int kt = 0; kt < T; ++kt) {
        if (kt + 1 < T) stage(kt + 1, cur ^ 1);
        f16x8 fa[4], fb[8];
#pragma unroll
        for (int rt = 0; rt < 4; ++rt) {
            int row = wm * 64 + rt * 16 + fr;
            int ad = row * 32 + ((q ^ ((row >> 1) & 3)) * 8);
            fa[rt] = __builtin_bit_cast(f16x8, *(const uint4*)&Ash[cur][ad]);
        }
#pragma unroll
        for (int cf = 0; cf < 8; ++cf) {
            int row = wn * 128 + cf * 16 + fr;
            int ad = row * 32 + ((q ^ ((row >> 1) & 3)) * 8);
            fb[cf] = __builtin_bit_cast(f16x8, *(const uint4*)&Bsh[cur][ad]);
        }
#pragma unroll
        for (int rt = 0; rt < 4; ++rt)
#pragma unroll
            for (int cf = 0; cf < 8; ++cf)
                acc[rt][cf] = __builtin_amdgcn_mfma_f32_16x16x32_f16(fb[cf], fa[rt], acc[rt][cf], 0, 0, 0);
        if (kt + 1 < T) __syncthreads();
        cur ^= 1;
    }

    // swapped epilogue: row = brow+wm*64+rt*16+fr ; cols = bcol+wn*128+cf*16+q*4 ..+3
#pragma unroll
    for (int rt = 0; rt < 4; ++rt) {
        int row = brow + wm * 64 + rt * 16 + fr;
        if (row >= M) continue;
#pragma unroll
        for (int cf = 0; cf < 8; ++cf) {
            int col0 = bcol + wn * 128 + cf * 16 + q * 4;
            float4 b4 = bias ? *(const float4*)(bias + col0) : make_float4(0.f, 0.f, 0.f, 0.f);
            float v0 = acc[rt][cf][0] + b4.x;
            float v1 = acc[rt][cf][1] + b4.y;
            float v2 = acc[rt][cf][2] + b4.z;
            float v3 = acc[rt][cf][3] + b4.w;
            if (act) { v0 = leaky(v0); v1 = leaky(v1); v2 = leaky(v2); v3 = leaky(v3); }
            ushort4 pk = make_ushort4(f2h(v0), f2h(v1), f2h(v2), f2h(v3));
            if (col0 < colsplit) *(ushort4*)(out1h + (size_t)row * n1 + col0) = pk;
            else                 *(ushort4*)(out2h + (size_t)row * n2 + (col0 - colsplit)) = pk;
        }
    }
}

// ---------------- fp16 MFMA GEMM: 128x64 tile, double-buffer, swapped epilogue -----
// Small-N variant for the layer-3 GEMM.
__global__ __launch_bounds__(256, 6) void k_gemm_s(
    int M, int nct,
    const u16* __restrict__ A1, const u16* __restrict__ B1, int K1,
    const float* __restrict__ bias, int act, int colsplit,
    u16* __restrict__ out1h, int n1, u16* __restrict__ out2h, int n2) {
    __shared__ u16 Ash[2][4096], Bsh[2][2048];
    const int tid = threadIdx.x;
    const int lane = tid & 63;
    const int w = tid >> 6;
    const int wm = w & 1, wn = w >> 1;
    const int fr = lane & 15;
    const int q = lane >> 4;

    const int mT = (M + 127) >> 7;
    const int lin = blockIdx.x;
    const int grp = lin / (8 * nct);
    const int idx = lin - grp * (8 * nct);
    const int ct = idx >> 3;
    const int s8 = idx & 7;
    const int rowt = grp * 8 + s8;
    if (rowt >= mT) return;
    const int brow = rowt * 128;
    const int bcol = ct * 64;

    const int T = K1 >> 5;

    const int sA0 = (w * 2 + 0) * 64 + lane;
    const int sA1 = (w * 2 + 1) * 64 + lane;
    const int rA0 = sA0 >> 2, gA0 = (sA0 & 3) ^ ((rA0 >> 1) & 3);
    const int rA1 = sA1 >> 2, gA1 = (sA1 & 3) ^ ((rA1 >> 1) & 3);
    int ar0 = brow + rA0; if (ar0 >= M) ar0 = M - 1;
    int ar1 = brow + rA1; if (ar1 >= M) ar1 = M - 1;
    const int sB = w * 64 + lane;
    const int rB = sB >> 2, gB = (sB & 3) ^ ((rB >> 1) & 3);
    const int br = bcol + rB;
    const int ubA0 = (w * 2 + 0) * 512;
    const int ubA1 = (w * 2 + 1) * 512;
    const int ubB  = w * 512;

    auto stage = [&](int kt, int buf) {
        int k0 = kt * 32;
        async_load16(A1 + (size_t)ar0 * K1 + k0 + gA0 * 8, &Ash[buf][ubA0]);
        async_load16(A1 + (size_t)ar1 * K1 + k0 + gA1 * 8, &Ash[buf][ubA1]);
        async_load16(B1 + (size_t)br  * K1 + k0 + gB  * 8, &Bsh[buf][ubB]);
    };

    f32x4 acc[4][2] = {};

    stage(0, 0);
    __syncthreads();

    int cur = 0;
    for (int kt = 0; kt < T; ++kt) {
        if (kt + 1 < T) stage(kt + 1, cur ^ 1);
        f16x8 fa[4], fb[2];
#pragma unroll
        for (int rt = 0; rt < 4; ++rt) {
            int row = wm * 64 + rt * 16 + fr;
            int ad = row * 32 + ((q ^ ((row >> 1) & 3)) * 8);
            fa[rt] = __builtin_bit_cast(f16x8, *(const uint4*)&Ash[cur][ad]);
        }
#pragma unroll
        for (int ctf = 0; ctf < 2; ++ctf) {
            int row = wn * 32 + ctf * 16 + fr;
            int ad = row * 32 + ((q ^ ((row >> 1) & 3)) * 8);
            fb[ctf] = __builtin_bit_cast(f16x8, *(const uint4*)&Bsh[cur][ad]);
        }
#pragma unroll
        for (int rt = 0; rt < 4; ++rt)
#pragma unroll
            for (int ctf = 0; ctf < 2; ++ctf)
                acc[rt][ctf] = __builtin_amdgcn_mfma_f32_16x16x32_f16(fb[ctf], fa[rt], acc[rt][ctf], 0, 0, 0);
        if (kt + 1 < T) __syncthreads();
        cur ^= 1;
    }

#pragma unroll
    for (int rt = 0; rt < 4; ++rt) {
        int row = brow + wm * 64 + rt * 16 + fr;
        if (row >= M) continue;
#pragma unroll
        for (int ctf = 0; ctf < 2; ++ctf) {
            int col0 = bcol + wn * 32 + ctf * 16 + q * 4;
            float4 b4 = bias ? *(const float4*)(bias + col0) : make_float4(0.f, 0.f, 0.f, 0.f);
            float v0 = acc[rt][ctf][0] + b4.x;
            float v1 = acc[rt][ctf][1] + b4.y;
            float v2 = acc[rt][ctf][2] + b4.z;
            float v3 = acc[rt][ctf][3] + b4.w;
            if (act) { v0 = leaky(v0); v1 = leaky(v1); v2 = leaky(v2); v3 = leaky(v3); }
            ushort4 pk = make_ushort4(f2h(v0), f2h(v1), f2h(v2), f2h(v3));
            if (col0 < colsplit) *(ushort4*)(out1h + (size_t)row * n1 + col0) = pk;
            else                 *(ushort4*)(out2h + (size_t)row * n2 + (col0 - colsplit)) = pk;
        }
    }
}

// ---------------- launch ----------------
extern "C" void kernel_launch(void* const* d_in, const int* in_sizes, int n_in,
                              void* d_out, int out_size, void* d_ws, size_t ws_size,
                              hipStream_t stream) {
    const float* x   = (const float*)d_in[0];
    const int*   ei  = (const int*)d_in[1];
    const float* W1l = (const float*)d_in[5];
    const float* b1  = (const float*)d_in[6];
    const float* W1r = (const float*)d_in[7];
    const float* W2l = (const float*)d_in[8];
    const float* b2  = (const float*)d_in[9];
    const float* W2r = (const float*)d_in[10];
    const float* W3l = (const float*)d_in[11];
    const float* b3  = (const float*)d_in[12];
    const float* W3r = (const float*)d_in[13];
    const float* Wp  = (const float*)d_in[14];
    const float* bp  = (const float*)d_in[15];
    const float* Wf1 = (const float*)d_in[16];
    const float* bf1 = (const float*)d_in[17];
    const float* Wf2 = (const float*)d_in[18];
    const float* bf2 = (const float*)d_in[19];
    float* out = (float*)d_out;
    (void)in_sizes; (void)n_in; (void)out_size; (void)ws_size;

    const int* src = ei;
    const int* dst = ei + N_EDGES;

    char* base = (char*)d_ws;
    size_t off = 0;
    auto alloc = [&](size_t bytes) -> void* {
        void* r = base + off;
        off = (off + bytes + 255) & ~(size_t)255;
        return r;
    };
    const size_t NN = N_NODES;
    int*   cnt    = (int*)alloc(NN * 4);
    int*   offs   = (int*)alloc((NN + 1) * 4);      // padded CSR offsets
    float* inv    = (float*)alloc(NN * 4);
    int*   bsum   = (int*)alloc(64 * 4);
    int*   erank  = (int*)alloc((size_t)N_EDGES * 4);               // per-edge rank in dst
    int*   pssrc  = (int*)alloc((size_t)(N_EDGES + 16 * N_NODES) * 4);  // padded src list
    u16* w1lp = (u16*)alloc(128 * 512 * 2);
    u16* w1rp = (u16*)alloc(128 * 512 * 2);
    u16* w2cp = (u16*)alloc(512 * 512 * 2);
    u16* w3cp = (u16*)alloc(128 * 256 * 2);
    // gathered tables carry one extra zeroed pad row (index N_NODES)
    u16* xp  = (u16*)alloc((NN + 1) * 128 * 2);
    u16* axp = (u16*)alloc(NN * 128 * 2);
    u16* h1p = (u16*)alloc(NN * 512 * 2);
    u16* z2h = (u16*)alloc((NN + 1) * 256 * 2);
    u16* y2h = (u16*)alloc(NN * 256 * 2);
    u16* h2p = (u16*)alloc(NN * 256 * 2);
    u16* z3h = (u16*)alloc((NN + 1) * 64 * 2);
    u16* y3h = (u16*)alloc(NN * 64 * 2);

    // CSR + prep (pad-row zeroing folded into k_prep)
    hipMemsetAsync(cnt, 0, NN * 4, stream);
    k_prep<<<3125 + 6250 + 1664 + 2, 256, 0, stream>>>(dst, cnt, erank, x, xp,
        W1l, W1r, W2l, W2r, W3l, W3r, w1lp, w1rp, w2cp, w3cp, z2h, z3h);
    const int nb = (N_NODES + 1023) / 1024;   // 49
    k_scan1<<<nb, 1024, 0, stream>>>(cnt, offs, bsum);
    k_scan3<<<(N_NODES + 255) / 256, 256, 0, stream>>>(cnt, offs, inv, pssrc, bsum, nb);
    k_fill<<<(N_EDGES / 4 + 255) / 256, 256, 0, stream>>>(src, dst, erank, offs, pssrc);

    const int aggGrid = N_NODES / 4;                   // 12500 exact (4 waves/block)
    const int mT = (N_NODES + 127) / 128;              // 391
    const int gridW = ((mT + 7) / 8) * 8 * 2;          // 784 (256-col wide tiles)
    const int grid2s = ((mT + 7) / 8) * 8 * 2;         // nct=2 (64-col tiles, N=128)

    // layer 1: aggX = mean-gather of xp (128 cols, full row per wave)
    k_agg<128, 0, 16, 4><<<aggGrid, 256, 0, stream>>>(
        xp, offs, pssrc, inv, nullptr, nullptr, axp);
    k_gemm_w<<<gridW, 256, 0, stream>>>(N_NODES, 2,
        axp, w1lp, 128, xp, w1rp, 128, b1, 1, 512, h1p, 512, nullptr, 0);

    // layer 2: [z2|y2] = h1 @ [W2l|W2r] (fp16); h2 = leaky(mean z2 + y2 + b2) (fp16)
    k_gemm_w<<<gridW, 256, 0, stream>>>(N_NODES, 2,
        h1p, w2cp, 512, nullptr, nullptr, 0, nullptr, 0, 256, z2h, 256, y2h, 256);
    k_agg<256, 2, 32, 4><<<aggGrid, 256, 0, stream>>>(
        z2h, offs, pssrc, inv, y2h, b2, h2p);

    // layer 3: [z3|y3] = h2 @ [W3l|W3r] (fp16); then agg+head fused -> out
    k_gemm_s<<<grid2s, 256, 0, stream>>>(N_NODES, 2,
        h2p, w3cp, 256, nullptr, 0, 64, z3h, 64, y3h, 64);
    k_agg_head<<<aggGrid, 256, 0, stream>>>(
        z3h, offs, pssrc, inv, y3h, b3, Wp, bp, Wf1, bf1, Wf2, bf2, out);
}

// Round 10
// 424.340 us; speedup vs baseline: 1.2543x; 1.2543x over previous
//
#include <hip/hip_runtime.h>
#include <hip/hip_fp16.h>

#define N_NODES 50000
#define N_EDGES 800000
#define SLOPE 0.15f

typedef unsigned short u16;
typedef __attribute__((ext_vector_type(8))) _Float16 f16x8;
typedef __attribute__((ext_vector_type(2))) _Float16 h16x2;
typedef __attribute__((ext_vector_type(4))) float f32x4;

static __device__ __forceinline__ float leaky(float v) { return v > 0.f ? v : SLOPE * v; }

static __device__ __forceinline__ u16 f2h(float v) {
    return __builtin_bit_cast(u16, __float2half(v));
}

// acc += lo_half + hi_half of u (fp16 pair), f32 accumulate via v_dot2_f32_f16
static __device__ __forceinline__ float dot2acc(unsigned int u, float c) {
    h16x2 one = {(_Float16)1.0f, (_Float16)1.0f};
    return __builtin_amdgcn_fdot2(__builtin_bit_cast(h16x2, u), one, c, false);
}

// async global->LDS 16B: HW writes lane's data to (wave-uniform lds base) + lane*16
static __device__ __forceinline__ void async_load16(const u16* g, u16* l) {
    __builtin_amdgcn_global_load_lds(
        (const __attribute__((address_space(1))) unsigned int*)g,
        (__attribute__((address_space(3))) unsigned int*)l, 16, 0, 0);
}

// ---------------- merged prep: edge count+rank | x->fp16 | weight transpose | padzero
// block ranges: [0,3125) count+rank; [3125,9375) xconv; [9375,11039) wconv; [11039,11041) pad
__global__ void k_prep(const int* __restrict__ dst, int* __restrict__ cnt,
                       int* __restrict__ erank,
                       const float* __restrict__ x, u16* __restrict__ xp,
                       const float* __restrict__ W1l, const float* __restrict__ W1r,
                       const float* __restrict__ W2l, const float* __restrict__ W2r,
                       const float* __restrict__ W3l, const float* __restrict__ W3r,
                       u16* w1lp, u16* w1rp, u16* w2cp, u16* w3cp,
                       u16* z2h, u16* z3h) {
    int b = blockIdx.x, tid = threadIdx.x;
    if (b < 3125) {
        int e = b * 256 + tid;
        if (e < N_EDGES) erank[e] = atomicAdd(&cnt[dst[e]], 1);  // rank within dst node
        return;
    }
    b -= 3125;
    if (b < 6250) {
        int i = b * 256 + tid;
        if (i >= N_NODES * 32) return;
        float4 v = ((const float4*)x)[i];
        ((ushort4*)xp)[i] = make_ushort4(f2h(v.x), f2h(v.y), f2h(v.z), f2h(v.w));
        return;
    }
    b -= 6250;
    if (b >= 1664) {   // pad-row zeroing: xp row N (128), z2h row N (256), z3h row N (64)
        int i = (b - 1664) * 256 + tid;
        if (i < 128)      xp[(size_t)N_NODES * 128 + i] = 0;
        else if (i < 384) z2h[(size_t)N_NODES * 256 + (i - 128)] = 0;
        else if (i < 448) z3h[(size_t)N_NODES * 64 + (i - 384)] = 0;
        return;
    }
    const float* W; u16* op; int K, N;
    if (b < 256)       { W = W1l; op = w1lp; K = 128; N = 512; }
    else if (b < 512)  { W = W1r; op = w1rp; K = 128; N = 512; b -= 256; }
    else if (b < 1024) { W = W2l; op = w2cp; K = 512; N = 256; b -= 512; }
    else if (b < 1536) { W = W2r; op = w2cp + 256 * 512; K = 512; N = 256; b -= 1024; }
    else if (b < 1600) { W = W3l; op = w3cp; K = 256; N = 64; b -= 1536; }
    else               { W = W3r; op = w3cp + 64 * 256; K = 256; N = 64; b -= 1600; }
    int i = b * 256 + tid;
    if (i >= K * N) return;
    int k = i / N, n = i - k * N;
    op[(size_t)n * K + k] = f2h(W[i]);   // W^T [N][K] fp16
}

// multi-block scan over PADDED counts (pad each node to multiple of 8 slots)
__global__ __launch_bounds__(1024) void k_scan1(const int* __restrict__ cnt,
                                                int* __restrict__ offs,
                                                int* __restrict__ bsum) {
    __shared__ int wsum[16];
    int tid = threadIdx.x, lane = tid & 63, wv = tid >> 6;
    int i = blockIdx.x * 1024 + tid;
    int c = (i < N_NODES) ? cnt[i] : 0;
    int orig = (c + 7) & ~7;            // padded count (mult of 8)
    int v = orig;
#pragma unroll
    for (int d = 1; d < 64; d <<= 1) {
        int t = __shfl_up(v, d, 64);
        if (lane >= d) v += t;
    }
    if (lane == 63) wsum[wv] = v;
    __syncthreads();
    if (wv == 0) {
        int s = (lane < 16) ? wsum[lane] : 0;
#pragma unroll
        for (int d = 1; d < 16; d <<= 1) {
            int t = __shfl_up(s, d, 64);
            if (lane >= d) s += t;
        }
        if (lane < 16) wsum[lane] = s;
        if (lane == 15) bsum[blockIdx.x] = s;
    }
    __syncthreads();
    int wpre = (wv == 0) ? 0 : wsum[wv - 1];
    if (i < N_NODES) offs[i] = v + wpre - orig;
}

// stage 2+3 merged (padded offsets; offs[N_NODES]=total) + per-node pad-sentinel fill
__global__ void k_scan3(const int* __restrict__ cnt, int* __restrict__ offs,
                        float* __restrict__ inv, int* __restrict__ pssrc,
                        const int* __restrict__ bsum, int nb) {
    __shared__ int sb[64];
    int tid = threadIdx.x;
    if (tid < 64) {
        int v = (tid < nb) ? bsum[tid] : 0;
        int s = v;
#pragma unroll
        for (int d = 1; d < 64; d <<= 1) {
            int t = __shfl_up(s, d, 64);
            if (tid >= d) s += t;
        }
        sb[tid] = s - v;
        if (blockIdx.x == 0 && tid == nb - 1) offs[N_NODES] = s;  // total padded
    }
    __syncthreads();
    int i = blockIdx.x * 256 + tid;
    if (i >= N_NODES) return;
    int c = cnt[i];
    int o = offs[i] + sb[i >> 10];
    offs[i] = o;
    inv[i] = 1.0f / (float)(c > 1 ? c : 1);
    int cp = (c + 7) & ~7;
    for (int j = c; j < cp; ++j) pssrc[o + j] = N_NODES;   // zero pad row sentinel
}

// atomic-free fill: pssrc[offs[dst]+rank] = src ; 4 edges/thread, fire-and-forget
__global__ void k_fill(const int* __restrict__ src, const int* __restrict__ dst,
                       const int* __restrict__ erank, const int* __restrict__ poffs,
                       int* __restrict__ pssrc) {
    int t = blockIdx.x * 256 + threadIdx.x;
    int e = t * 4;
    if (e + 3 >= N_EDGES) {
        for (; e < N_EDGES; ++e) pssrc[poffs[dst[e]] + erank[e]] = src[e];
        return;
    }
    int4 d4 = *(const int4*)&dst[e];
    int4 s4 = *(const int4*)&src[e];
    int4 r4 = *(const int4*)&erank[e];
    int p0 = poffs[d4.x] + r4.x;
    int p1 = poffs[d4.y] + r4.y;
    int p2 = poffs[d4.z] + r4.z;
    int p3 = poffs[d4.w] + r4.w;
    pssrc[p0] = s4.x;
    pssrc[p1] = s4.y;
    pssrc[p2] = s4.z;
    pssrc[p3] = s4.w;
}

// ---------------- padded-CSR mean aggregation, full-row waves --------------------
// One wave per node, LPE lanes per edge (LPE*8 = STRIDE cols), G=64/LPE edge groups,
// U consecutive edges unrolled per lane. No masks (CSR padded to 8, zero pad row;
// per-lane e<end exit covers the 8-remainder for G*U=16 configs).
// EPI: 0 = mean -> fp16 outh; 2 = leaky(mean+y+bias) -> fp16 outh; 3 = -> f32 outf
template <int STRIDE, int EPI, int LPE, int U>
__global__ __launch_bounds__(256) void k_agg(const u16* __restrict__ tbl,
                                             const int* __restrict__ poffs,
                                             const int* __restrict__ pssrc,
                                             const float* __restrict__ inv,
                                             const u16* __restrict__ y,
                                             const float* __restrict__ bias,
                                             u16* __restrict__ outh,
                                             float* __restrict__ outf) {
    constexpr int G = 64 / LPE;
    int wid = (blockIdx.x * 256 + threadIdx.x) >> 6;
    if (wid >= N_NODES) return;
    int lane = threadIdx.x & 63;
    int g = lane / LPE;
    int cl = lane % LPE;
    int beg = poffs[wid], end = poffs[wid + 1];
    const u16* colbase = tbl + cl * 8;
    float acc[8] = {};
    for (int e = beg + g * U; e < end; e += G * U) {
        int idx[U];
        if constexpr (U == 4) {
            int4 t4 = *(const int4*)&pssrc[e];
            idx[0] = t4.x; idx[1] = t4.y; idx[2] = t4.z; idx[3] = t4.w;
        } else {
            int2 t2 = *(const int2*)&pssrc[e];
            idx[0] = t2.x; idx[1] = t2.y;
        }
        uint4 rv[U];
#pragma unroll
        for (int j = 0; j < U; ++j)
            rv[j] = *(const uint4*)(colbase + (size_t)idx[j] * STRIDE);
#pragma unroll
        for (int p = 0; p < U / 2; ++p) {
            const unsigned int* a = (const unsigned int*)&rv[2 * p];
            const unsigned int* b = (const unsigned int*)&rv[2 * p + 1];
#pragma unroll
            for (int t = 0; t < 4; ++t) {
                // lo = (a.col2t, b.col2t), hi = (a.col2t+1, b.col2t+1)
                unsigned int lo = __builtin_amdgcn_perm(b[t], a[t], 0x05040100u);
                unsigned int hi = __builtin_amdgcn_perm(b[t], a[t], 0x07060302u);
                acc[2 * t + 0] = dot2acc(lo, acc[2 * t + 0]);
                acc[2 * t + 1] = dot2acc(hi, acc[2 * t + 1]);
            }
        }
    }
    // reduce across the G edge groups (group stride = LPE lanes)
#pragma unroll
    for (int m = LPE; m < 64; m <<= 1)
#pragma unroll
        for (int t = 0; t < 8; ++t) acc[t] += __shfl_xor(acc[t], m, 64);
    if (g != 0) return;
    float wv = inv[wid];
    const size_t ob = (size_t)wid * STRIDE + cl * 8;
    float v[8];
    if constexpr (EPI == 0) {
#pragma unroll
        for (int t = 0; t < 8; ++t) v[t] = acc[t] * wv;
    } else {
        uint4 yv4 = *(const uint4*)(y + ob);
        const __half2* yp = (const __half2*)&yv4;
        float4 b0 = *(const float4*)(bias + cl * 8);
        float4 b1 = *(const float4*)(bias + cl * 8 + 4);
        float bb[8] = {b0.x, b0.y, b0.z, b0.w, b1.x, b1.y, b1.z, b1.w};
#pragma unroll
        for (int t = 0; t < 4; ++t) {
            float2 f = __half22float2(yp[t]);
            v[t * 2 + 0] = leaky(acc[t * 2 + 0] * wv + f.x + bb[t * 2 + 0]);
            v[t * 2 + 1] = leaky(acc[t * 2 + 1] * wv + f.y + bb[t * 2 + 1]);
        }
    }
    if constexpr (EPI == 3) {
        *(float4*)(outf + ob)     = make_float4(v[0], v[1], v[2], v[3]);
        *(float4*)(outf + ob + 4) = make_float4(v[4], v[5], v[6], v[7]);
    } else {
        *(ushort4*)(outh + ob)     = make_ushort4(f2h(v[0]), f2h(v[1]), f2h(v[2]), f2h(v[3]));
        *(ushort4*)(outh + ob + 4) = make_ushort4(f2h(v[4]), f2h(v[5]), f2h(v[6]), f2h(v[7]));
    }
}

// ---------------- fp16 MFMA GEMM: 128x128 tile, double-buffer, SWAPPED epilogue ----
// R8-measured (60.9us). MFMA operands swapped (mfma(fb,fa)) so the accumulator holds
// C[row=base+fr][col=base+q*4+reg]: one ushort4 (8B) store per frag.
__global__ __launch_bounds__(256, 5) void k_gemm_f(
    int M, int nct,
    const u16* __restrict__ A1, const u16* __restrict__ B1, int K1,
    const u16* __restrict__ A2, const u16* __restrict__ B2, int K2,
    const float* __restrict__ bias, int act, int colsplit,
    u16* __restrict__ out1h, int n1, u16* __restrict__ out2h, int n2) {
    __shared__ u16 Ash[2][4096], Bsh[2][4096];
    const int tid = threadIdx.x;
    const int lane = tid & 63;
    const int w = tid >> 6;
    const int wm = w & 1, wn = w >> 1;
    const int fr = lane & 15;
    const int q = lane >> 4;

    const int mT = (M + 127) >> 7;
    const int lin = blockIdx.x;
    const int grp = lin / (8 * nct);
    const int idx = lin - grp * (8 * nct);
    const int ct = idx >> 3;
    const int s8 = idx & 7;
    const int rowt = grp * 8 + s8;
    if (rowt >= mT) return;
    const int brow = rowt * 128;
    const int bcol = ct * 128;

    const int T1 = K1 >> 5, T = T1 + (K2 >> 5);

    const int c0 = (w * 2 + 0) * 64 + lane;
    const int c1 = (w * 2 + 1) * 64 + lane;
    const int r0 = c0 >> 2, g0 = (c0 & 3) ^ ((r0 >> 1) & 3);
    const int r1 = c1 >> 2, g1 = (c1 & 3) ^ ((r1 >> 1) & 3);
    int ar0 = brow + r0; if (ar0 >= M) ar0 = M - 1;
    int ar1 = brow + r1; if (ar1 >= M) ar1 = M - 1;
    const int br0 = bcol + r0, br1 = bcol + r1;
    const int ub0 = (w * 2 + 0) * 512;
    const int ub1 = (w * 2 + 1) * 512;

    auto stage = [&](int kt, int buf) {
        const u16 *A, *B; int K, k0;
        if (kt < T1) { A = A1; B = B1; K = K1; k0 = kt * 32; }
        else         { A = A2; B = B2; K = K2; k0 = (kt - T1) * 32; }
        async_load16(A + (size_t)ar0 * K + k0 + g0 * 8, &Ash[buf][ub0]);
        async_load16(A + (size_t)ar1 * K + k0 + g1 * 8, &Ash[buf][ub1]);
        async_load16(B + (size_t)br0 * K + k0 + g0 * 8, &Bsh[buf][ub0]);
        async_load16(B + (size_t)br1 * K + k0 + g1 * 8, &Bsh[buf][ub1]);
    };

    f32x4 acc[4][4] = {};

    // prologue: tile 0 into buf 0
    stage(0, 0);
    __syncthreads();               // vmcnt(0) drain + barrier

    int cur = 0;
    for (int kt = 0; kt < T; ++kt) {
        if (kt + 1 < T) stage(kt + 1, cur ^ 1);   // prefetch in flight under compute
        f16x8 fa[4], fb[4];
#pragma unroll
        for (int rt = 0; rt < 4; ++rt) {
            int row = wm * 64 + rt * 16 + fr;
            int ad = row * 32 + ((q ^ ((row >> 1) & 3)) * 8);
            fa[rt] = __builtin_bit_cast(f16x8, *(const uint4*)&Ash[cur][ad]);
        }
#pragma unroll
        for (int ctf = 0; ctf < 4; ++ctf) {
            int row = wn * 64 + ctf * 16 + fr;
            int ad = row * 32 + ((q ^ ((row >> 1) & 3)) * 8);
            fb[ctf] = __builtin_bit_cast(f16x8, *(const uint4*)&Bsh[cur][ad]);
        }
#pragma unroll
        for (int rt = 0; rt < 4; ++rt)
#pragma unroll
            for (int ctf = 0; ctf < 4; ++ctf)
                acc[rt][ctf] = __builtin_amdgcn_mfma_f32_16x16x32_f16(fb[ctf], fa[rt], acc[rt][ctf], 0, 0, 0);
        if (kt + 1 < T) __syncthreads();          // drain prefetch + protect buf reuse
        cur ^= 1;
    }

    // swapped epilogue: row = brow+wm*64+rt*16+fr ; cols = bcol+wn*64+ctf*16+q*4 ..+3
#pragma unroll
    for (int rt = 0; rt < 4; ++rt) {
        int row = brow + wm * 64 + rt * 16 + fr;
        if (row >= M) continue;
#pragma unroll
        for (int ctf = 0; ctf < 4; ++ctf) {
            int col0 = bcol + wn * 64 + ctf * 16 + q * 4;
            float4 b4 = bias ? *(const float4*)(bias + col0) : make_float4(0.f, 0.f, 0.f, 0.f);
            float v0 = acc[rt][ctf][0] + b4.x;
            float v1 = acc[rt][ctf][1] + b4.y;
            float v2 = acc[rt][ctf][2] + b4.z;
            float v3 = acc[rt][ctf][3] + b4.w;
            if (act) { v0 = leaky(v0); v1 = leaky(v1); v2 = leaky(v2); v3 = leaky(v3); }
            ushort4 pk = make_ushort4(f2h(v0), f2h(v1), f2h(v2), f2h(v3));
            if (col0 < colsplit) *(ushort4*)(out1h + (size_t)row * n1 + col0) = pk;
            else                 *(ushort4*)(out2h + (size_t)row * n2 + (col0 - colsplit)) = pk;
        }
    }
}

// ---------------- fp16 MFMA GEMM: 128x64 tile, double-buffer, swapped epilogue -----
// Small-N variant for the layer-3 GEMM.
__global__ __launch_bounds__(256, 6) void k_gemm_s(
    int M, int nct,
    const u16* __restrict__ A1, const u16* __restrict__ B1, int K1,
    const float* __restrict__ bias, int act, int colsplit,
    u16* __restrict__ out1h, int n1, u16* __restrict__ out2h, int n2) {
    __shared__ u16 Ash[2][4096], Bsh[2][2048];
    const int tid = threadIdx.x;
    const int lane = tid & 63;
    const int w = tid >> 6;
    const int wm = w & 1, wn = w >> 1;
    const int fr = lane & 15;
    const int q = lane >> 4;

    const int mT = (M + 127) >> 7;
    const int lin = blockIdx.x;
    const int grp = lin / (8 * nct);
    const int idx = lin - grp * (8 * nct);
    const int ct = idx >> 3;
    const int s8 = idx & 7;
    const int rowt = grp * 8 + s8;
    if (rowt >= mT) return;
    const int brow = rowt * 128;
    const int bcol = ct * 64;

    const int T = K1 >> 5;

    const int sA0 = (w * 2 + 0) * 64 + lane;
    const int sA1 = (w * 2 + 1) * 64 + lane;
    const int rA0 = sA0 >> 2, gA0 = (sA0 & 3) ^ ((rA0 >> 1) & 3);
    const int rA1 = sA1 >> 2, gA1 = (sA1 & 3) ^ ((rA1 >> 1) & 3);
    int ar0 = brow + rA0; if (ar0 >= M) ar0 = M - 1;
    int ar1 = brow + rA1; if (ar1 >= M) ar1 = M - 1;
    const int sB = w * 64 + lane;
    const int rB = sB >> 2, gB = (sB & 3) ^ ((rB >> 1) & 3);
    const int br = bcol + rB;
    const int ubA0 = (w * 2 + 0) * 512;
    const int ubA1 = (w * 2 + 1) * 512;
    const int ubB  = w * 512;

    auto stage = [&](int kt, int buf) {
        int k0 = kt * 32;
        async_load16(A1 + (size_t)ar0 * K1 + k0 + gA0 * 8, &Ash[buf][ubA0]);
        async_load16(A1 + (size_t)ar1 * K1 + k0 + gA1 * 8, &Ash[buf][ubA1]);
        async_load16(B1 + (size_t)br  * K1 + k0 + gB  * 8, &Bsh[buf][ubB]);
    };

    f32x4 acc[4][2] = {};

    stage(0, 0);
    __syncthreads();

    int cur = 0;
    for (int kt = 0; kt < T; ++kt) {
        if (kt + 1 < T) stage(kt + 1, cur ^ 1);
        f16x8 fa[4], fb[2];
#pragma unroll
        for (int rt = 0; rt < 4; ++rt) {
            int row = wm * 64 + rt * 16 + fr;
            int ad = row * 32 + ((q ^ ((row >> 1) & 3)) * 8);
            fa[rt] = __builtin_bit_cast(f16x8, *(const uint4*)&Ash[cur][ad]);
        }
#pragma unroll
        for (int ctf = 0; ctf < 2; ++ctf) {
            int row = wn * 32 + ctf * 16 + fr;
            int ad = row * 32 + ((q ^ ((row >> 1) & 3)) * 8);
            fb[ctf] = __builtin_bit_cast(f16x8, *(const uint4*)&Bsh[cur][ad]);
        }
#pragma unroll
        for (int rt = 0; rt < 4; ++rt)
#pragma unroll
            for (int ctf = 0; ctf < 2; ++ctf)
                acc[rt][ctf] = __builtin_amdgcn_mfma_f32_16x16x32_f16(fb[ctf], fa[rt], acc[rt][ctf], 0, 0, 0);
        if (kt + 1 < T) __syncthreads();
        cur ^= 1;
    }

#pragma unroll
    for (int rt = 0; rt < 4; ++rt) {
        int row = brow + wm * 64 + rt * 16 + fr;
        if (row >= M) continue;
#pragma unroll
        for (int ctf = 0; ctf < 2; ++ctf) {
            int col0 = bcol + wn * 32 + ctf * 16 + q * 4;
            float4 b4 = bias ? *(const float4*)(bias + col0) : make_float4(0.f, 0.f, 0.f, 0.f);
            float v0 = acc[rt][ctf][0] + b4.x;
            float v1 = acc[rt][ctf][1] + b4.y;
            float v2 = acc[rt][ctf][2] + b4.z;
            float v3 = acc[rt][ctf][3] + b4.w;
            if (act) { v0 = leaky(v0); v1 = leaky(v1); v2 = leaky(v2); v3 = leaky(v3); }
            ushort4 pk = make_ushort4(f2h(v0), f2h(v1), f2h(v2), f2h(v3));
            if (col0 < colsplit) *(ushort4*)(out1h + (size_t)row * n1 + col0) = pk;
            else                 *(ushort4*)(out2h + (size_t)row * n2 + (col0 - colsplit)) = pk;
        }
    }
}

// ---------------- fused head: h3 -> pre_fc -> leaky(fc1) -> fc2 ------
__global__ __launch_bounds__(256) void k_head(const float* __restrict__ h3,
                                              const float* __restrict__ Wp, const float* __restrict__ bp,
                                              const float* __restrict__ Wf1, const float* __restrict__ bf1,
                                              const float* __restrict__ Wf2, const float* __restrict__ bf2,
                                              float* __restrict__ out) {
    __shared__ float sWp[64 * 32], sW1[32 * 32], sW2[32 * 2];
    __shared__ float sbp[32], sb1[32], sb2[2];
    int tid = threadIdx.x;
    for (int i = tid; i < 64 * 32; i += 256) sWp[i] = Wp[i];
    for (int i = tid; i < 32 * 32; i += 256) sW1[i] = Wf1[i];
    for (int i = tid; i < 64; i += 256) sW2[i] = Wf2[i];
    if (tid < 32) { sbp[tid] = bp[tid]; sb1[tid] = bf1[tid]; }
    if (tid < 2) sb2[tid] = bf2[tid];
    __syncthreads();
    int row = blockIdx.x * 256 + tid;
    if (row >= N_NODES) return;
    const float4* h4v = (const float4*)(h3 + (size_t)row * 64);
    float xr[64];
#pragma unroll
    for (int i = 0; i < 16; ++i) {
        float4 v = h4v[i];
        xr[i * 4 + 0] = v.x; xr[i * 4 + 1] = v.y;
        xr[i * 4 + 2] = v.z; xr[i * 4 + 3] = v.w;
    }
    float h4[32];
    for (int o = 0; o < 32; ++o) {
        float s = sbp[o];
#pragma unroll
        for (int i = 0; i < 64; ++i) s += xr[i] * sWp[i * 32 + o];
        h4[o] = s;
    }
    float h5[32];
    for (int o = 0; o < 32; ++o) {
        float s = sb1[o];
#pragma unroll
        for (int i = 0; i < 32; ++i) s += h4[i] * sW1[i * 32 + o];
        h5[o] = leaky(s);
    }
#pragma unroll
    for (int o = 0; o < 2; ++o) {
        float s = sb2[o];
#pragma unroll
        for (int i = 0; i < 32; ++i) s += h5[i] * sW2[i * 2 + o];
        out[(size_t)row * 2 + o] = s;
    }
}

// ---------------- launch ----------------
extern "C" void kernel_launch(void* const* d_in, const int* in_sizes, int n_in,
                              void* d_out, int out_size, void* d_ws, size_t ws_size,
                              hipStream_t stream) {
    const float* x   = (const float*)d_in[0];
    const int*   ei  = (const int*)d_in[1];
    const float* W1l = (const float*)d_in[5];
    const float* b1  = (const float*)d_in[6];
    const float* W1r = (const float*)d_in[7];
    const float* W2l = (const float*)d_in[8];
    const float* b2  = (const float*)d_in[9];
    const float* W2r = (const float*)d_in[10];
    const float* W3l = (const float*)d_in[11];
    const float* b3  = (const float*)d_in[12];
    const float* W3r = (const float*)d_in[13];
    const float* Wp  = (const float*)d_in[14];
    const float* bp  = (const float*)d_in[15];
    const float* Wf1 = (const float*)d_in[16];
    const float* bf1 = (const float*)d_in[17];
    const float* Wf2 = (const float*)d_in[18];
    const float* bf2 = (const float*)d_in[19];
    float* out = (float*)d_out;
    (void)in_sizes; (void)n_in; (void)out_size; (void)ws_size;

    const int* src = ei;
    const int* dst = ei + N_EDGES;

    char* base = (char*)d_ws;
    size_t off = 0;
    auto alloc = [&](size_t bytes) -> void* {
        void* r = base + off;
        off = (off + bytes + 255) & ~(size_t)255;
        return r;
    };
    const size_t NN = N_NODES;
    int*   cnt    = (int*)alloc(NN * 4);
    int*   offs   = (int*)alloc((NN + 1) * 4);      // padded CSR offsets
    float* inv    = (float*)alloc(NN * 4);
    int*   bsum   = (int*)alloc(64 * 4);
    int*   erank  = (int*)alloc((size_t)N_EDGES * 4);               // per-edge rank in dst
    int*   pssrc  = (int*)alloc((size_t)(N_EDGES + 8 * N_NODES) * 4);   // padded src list
    u16* w1lp = (u16*)alloc(128 * 512 * 2);
    u16* w1rp = (u16*)alloc(128 * 512 * 2);
    u16* w2cp = (u16*)alloc(512 * 512 * 2);
    u16* w3cp = (u16*)alloc(128 * 256 * 2);
    // gathered tables carry one extra zeroed pad row (index N_NODES)
    u16* xp  = (u16*)alloc((NN + 1) * 128 * 2);
    u16* axp = (u16*)alloc(NN * 128 * 2);
    u16* h1p = (u16*)alloc(NN * 512 * 2);
    u16* z2h = (u16*)alloc((NN + 1) * 256 * 2);
    u16* y2h = (u16*)alloc(NN * 256 * 2);
    u16* h2p = (u16*)alloc(NN * 256 * 2);
    u16* z3h = (u16*)alloc((NN + 1) * 64 * 2);
    u16* y3h = (u16*)alloc(NN * 64 * 2);
    float* h3f = (float*)alloc(NN * 64 * 4);

    // CSR + prep (pad-row zeroing folded into k_prep)
    hipMemsetAsync(cnt, 0, NN * 4, stream);
    k_prep<<<3125 + 6250 + 1664 + 2, 256, 0, stream>>>(dst, cnt, erank, x, xp,
        W1l, W1r, W2l, W2r, W3l, W3r, w1lp, w1rp, w2cp, w3cp, z2h, z3h);
    const int nb = (N_NODES + 1023) / 1024;   // 49
    k_scan1<<<nb, 1024, 0, stream>>>(cnt, offs, bsum);
    k_scan3<<<(N_NODES + 255) / 256, 256, 0, stream>>>(cnt, offs, inv, pssrc, bsum, nb);
    k_fill<<<(N_EDGES / 4 + 255) / 256, 256, 0, stream>>>(src, dst, erank, offs, pssrc);

    const int aggGrid = N_NODES / 4;                   // 12500 exact (4 waves/block)
    const int mT = (N_NODES + 127) / 128;              // 391
    const int grid4 = ((mT + 7) / 8) * 32;             // nct=4 (128-col tiles, N=512)
    const int grid2s = ((mT + 7) / 8) * 8 * 2;         // nct=2 (64-col tiles, N=128)

    // layer 1: aggX = mean-gather of xp (128 cols, full row per wave)
    k_agg<128, 0, 16, 4><<<aggGrid, 256, 0, stream>>>(
        xp, offs, pssrc, inv, nullptr, nullptr, axp, nullptr);
    k_gemm_f<<<grid4, 256, 0, stream>>>(N_NODES, 4,
        axp, w1lp, 128, xp, w1rp, 128, b1, 1, 512, h1p, 512, nullptr, 0);

    // layer 2: [z2|y2] = h1 @ [W2l|W2r] (fp16); h2 = leaky(mean z2 + y2 + b2) (fp16)
    k_gemm_f<<<grid4, 256, 0, stream>>>(N_NODES, 4,
        h1p, w2cp, 512, nullptr, nullptr, 0, nullptr, 0, 256, z2h, 256, y2h, 256);
    k_agg<256, 2, 32, 4><<<aggGrid, 256, 0, stream>>>(
        z2h, offs, pssrc, inv, y2h, b2, h2p, nullptr);

    // layer 3: [z3|y3] = h2 @ [W3l|W3r] (fp16); h3 = leaky(mean z3 + y3 + b3) (f32)
    k_gemm_s<<<grid2s, 256, 0, stream>>>(N_NODES, 2,
        h2p, w3cp, 256, nullptr, 0, 64, z3h, 64, y3h, 64);
    k_agg<64, 3, 8, 2><<<aggGrid, 256, 0, stream>>>(
        z3h, offs, pssrc, inv, y3h, b3, nullptr, h3f);

    // head: h3 -> pre_fc -> leaky(fc1) -> fc2
    k_head<<<(N_NODES + 255) / 256, 256, 0, stream>>>(h3f,
        Wp, bp, Wf1, bf1, Wf2, bf2, out);
}

// Round 11
// 394.303 us; speedup vs baseline: 1.3499x; 1.0762x over previous
//
#include <hip/hip_runtime.h>
#include <hip/hip_fp16.h>

#define N_NODES 50000
#define N_EDGES 800000
#define SLOPE 0.15f

typedef unsigned short u16;
typedef __attribute__((ext_vector_type(8))) _Float16 f16x8;
typedef __attribute__((ext_vector_type(2))) _Float16 h16x2;
typedef __attribute__((ext_vector_type(4))) float f32x4;

static __device__ __forceinline__ float leaky(float v) { return v > 0.f ? v : SLOPE * v; }

static __device__ __forceinline__ u16 f2h(float v) {
    return __builtin_bit_cast(u16, __float2half(v));
}

// acc += lo_half + hi_half of u (fp16 pair), f32 accumulate via v_dot2_f32_f16
static __device__ __forceinline__ float dot2acc(unsigned int u, float c) {
    h16x2 one = {(_Float16)1.0f, (_Float16)1.0f};
    return __builtin_amdgcn_fdot2(__builtin_bit_cast(h16x2, u), one, c, false);
}

// async global->LDS 16B: HW writes lane's data to (wave-uniform lds base) + lane*16
static __device__ __forceinline__ void async_load16(const u16* g, u16* l) {
    __builtin_amdgcn_global_load_lds(
        (const __attribute__((address_space(1))) unsigned int*)g,
        (__attribute__((address_space(3))) unsigned int*)l, 16, 0, 0);
}

// ---------------- merged prep: edge count+rank | x->fp16 | weight transpose | padzero
// block ranges: [0,3125) count+rank; [3125,9375) xconv; [9375,11039) wconv; [11039,11041) pad
__global__ void k_prep(const int* __restrict__ dst, int* __restrict__ cnt,
                       int* __restrict__ erank,
                       const float* __restrict__ x, u16* __restrict__ xp,
                       const float* __restrict__ W1l, const float* __restrict__ W1r,
                       const float* __restrict__ W2l, const float* __restrict__ W2r,
                       const float* __restrict__ W3l, const float* __restrict__ W3r,
                       u16* w1lp, u16* w1rp, u16* w2cp, u16* w3cp,
                       u16* z2h, u16* z3h) {
    int b = blockIdx.x, tid = threadIdx.x;
    if (b < 3125) {
        int e = b * 256 + tid;
        if (e < N_EDGES) erank[e] = atomicAdd(&cnt[dst[e]], 1);  // rank within dst node
        return;
    }
    b -= 3125;
    if (b < 6250) {
        int i = b * 256 + tid;
        if (i >= N_NODES * 32) return;
        float4 v = ((const float4*)x)[i];
        ((ushort4*)xp)[i] = make_ushort4(f2h(v.x), f2h(v.y), f2h(v.z), f2h(v.w));
        return;
    }
    b -= 6250;
    if (b >= 1664) {   // pad-row zeroing: xp row N (128), z2h row N (256), z3h row N (64)
        int i = (b - 1664) * 256 + tid;
        if (i < 128)      xp[(size_t)N_NODES * 128 + i] = 0;
        else if (i < 384) z2h[(size_t)N_NODES * 256 + (i - 128)] = 0;
        else if (i < 448) z3h[(size_t)N_NODES * 64 + (i - 384)] = 0;
        return;
    }
    const float* W; u16* op; int K, N;
    if (b < 256)       { W = W1l; op = w1lp; K = 128; N = 512; }
    else if (b < 512)  { W = W1r; op = w1rp; K = 128; N = 512; b -= 256; }
    else if (b < 1024) { W = W2l; op = w2cp; K = 512; N = 256; b -= 512; }
    else if (b < 1536) { W = W2r; op = w2cp + 256 * 512; K = 512; N = 256; b -= 1024; }
    else if (b < 1600) { W = W3l; op = w3cp; K = 256; N = 64; b -= 1536; }
    else               { W = W3r; op = w3cp + 64 * 256; K = 256; N = 64; b -= 1600; }
    int i = b * 256 + tid;
    if (i >= K * N) return;
    int k = i / N, n = i - k * N;
    op[(size_t)n * K + k] = f2h(W[i]);   // W^T [N][K] fp16
}

// multi-block scan over PADDED counts (pad each node to multiple of 8 slots)
__global__ __launch_bounds__(1024) void k_scan1(const int* __restrict__ cnt,
                                                int* __restrict__ offs,
                                                int* __restrict__ bsum) {
    __shared__ int wsum[16];
    int tid = threadIdx.x, lane = tid & 63, wv = tid >> 6;
    int i = blockIdx.x * 1024 + tid;
    int c = (i < N_NODES) ? cnt[i] : 0;
    int orig = (c + 7) & ~7;            // padded count (mult of 8)
    int v = orig;
#pragma unroll
    for (int d = 1; d < 64; d <<= 1) {
        int t = __shfl_up(v, d, 64);
        if (lane >= d) v += t;
    }
    if (lane == 63) wsum[wv] = v;
    __syncthreads();
    if (wv == 0) {
        int s = (lane < 16) ? wsum[lane] : 0;
#pragma unroll
        for (int d = 1; d < 16; d <<= 1) {
            int t = __shfl_up(s, d, 64);
            if (lane >= d) s += t;
        }
        if (lane < 16) wsum[lane] = s;
        if (lane == 15) bsum[blockIdx.x] = s;
    }
    __syncthreads();
    int wpre = (wv == 0) ? 0 : wsum[wv - 1];
    if (i < N_NODES) offs[i] = v + wpre - orig;
}

// stage 2+3 merged (padded offsets; offs[N_NODES]=total) + per-node pad-sentinel fill
__global__ void k_scan3(const int* __restrict__ cnt, int* __restrict__ offs,
                        float* __restrict__ inv, int* __restrict__ pssrc,
                        const int* __restrict__ bsum, int nb) {
    __shared__ int sb[64];
    int tid = threadIdx.x;
    if (tid < 64) {
        int v = (tid < nb) ? bsum[tid] : 0;
        int s = v;
#pragma unroll
        for (int d = 1; d < 64; d <<= 1) {
            int t = __shfl_up(s, d, 64);
            if (tid >= d) s += t;
        }
        sb[tid] = s - v;
        if (blockIdx.x == 0 && tid == nb - 1) offs[N_NODES] = s;  // total padded
    }
    __syncthreads();
    int i = blockIdx.x * 256 + tid;
    if (i >= N_NODES) return;
    int c = cnt[i];
    int o = offs[i] + sb[i >> 10];
    offs[i] = o;
    inv[i] = 1.0f / (float)(c > 1 ? c : 1);
    int cp = (c + 7) & ~7;
    for (int j = c; j < cp; ++j) pssrc[o + j] = N_NODES;   // zero pad row sentinel
}

// atomic-free fill: pssrc[offs[dst]+rank] = src ; 4 edges/thread, fire-and-forget
__global__ void k_fill(const int* __restrict__ src, const int* __restrict__ dst,
                       const int* __restrict__ erank, const int* __restrict__ poffs,
                       int* __restrict__ pssrc) {
    int t = blockIdx.x * 256 + threadIdx.x;
    int e = t * 4;
    if (e + 3 >= N_EDGES) {
        for (; e < N_EDGES; ++e) pssrc[poffs[dst[e]] + erank[e]] = src[e];
        return;
    }
    int4 d4 = *(const int4*)&dst[e];
    int4 s4 = *(const int4*)&src[e];
    int4 r4 = *(const int4*)&erank[e];
    int p0 = poffs[d4.x] + r4.x;
    int p1 = poffs[d4.y] + r4.y;
    int p2 = poffs[d4.z] + r4.z;
    int p3 = poffs[d4.w] + r4.w;
    pssrc[p0] = s4.x;
    pssrc[p1] = s4.y;
    pssrc[p2] = s4.z;
    pssrc[p3] = s4.w;
}

// ---------------- padded-CSR mean aggregation, full-row waves --------------------
// One wave per node, LPE lanes per edge (LPE*8 = STRIDE cols), G=64/LPE edge groups,
// U consecutive edges unrolled per lane. No masks (CSR padded to 8, zero pad row;
// per-lane e<end exit covers the 8-remainder for G*U=16 configs).
// EPI: 0 = mean -> fp16 outh; 2 = leaky(mean+y+bias) -> fp16 outh; 3 = -> f32 outf
template <int STRIDE, int EPI, int LPE, int U>
__global__ __launch_bounds__(256) void k_agg(const u16* __restrict__ tbl,
                                             const int* __restrict__ poffs,
                                             const int* __restrict__ pssrc,
                                             const float* __restrict__ inv,
                                             const u16* __restrict__ y,
                                             const float* __restrict__ bias,
                                             u16* __restrict__ outh,
                                             float* __restrict__ outf) {
    constexpr int G = 64 / LPE;
    int wid = (blockIdx.x * 256 + threadIdx.x) >> 6;
    if (wid >= N_NODES) return;
    int lane = threadIdx.x & 63;
    int g = lane / LPE;
    int cl = lane % LPE;
    int beg = poffs[wid], end = poffs[wid + 1];
    const u16* colbase = tbl + cl * 8;
    float acc[8] = {};
    for (int e = beg + g * U; e < end; e += G * U) {
        int idx[U];
        if constexpr (U == 4) {
            int4 t4 = *(const int4*)&pssrc[e];
            idx[0] = t4.x; idx[1] = t4.y; idx[2] = t4.z; idx[3] = t4.w;
        } else {
            int2 t2 = *(const int2*)&pssrc[e];
            idx[0] = t2.x; idx[1] = t2.y;
        }
        uint4 rv[U];
#pragma unroll
        for (int j = 0; j < U; ++j)
            rv[j] = *(const uint4*)(colbase + (size_t)idx[j] * STRIDE);
#pragma unroll
        for (int p = 0; p < U / 2; ++p) {
            const unsigned int* a = (const unsigned int*)&rv[2 * p];
            const unsigned int* b = (const unsigned int*)&rv[2 * p + 1];
#pragma unroll
            for (int t = 0; t < 4; ++t) {
                // lo = (a.col2t, b.col2t), hi = (a.col2t+1, b.col2t+1)
                unsigned int lo = __builtin_amdgcn_perm(b[t], a[t], 0x05040100u);
                unsigned int hi = __builtin_amdgcn_perm(b[t], a[t], 0x07060302u);
                acc[2 * t + 0] = dot2acc(lo, acc[2 * t + 0]);
                acc[2 * t + 1] = dot2acc(hi, acc[2 * t + 1]);
            }
        }
    }
    // reduce across the G edge groups (group stride = LPE lanes)
#pragma unroll
    for (int m = LPE; m < 64; m <<= 1)
#pragma unroll
        for (int t = 0; t < 8; ++t) acc[t] += __shfl_xor(acc[t], m, 64);
    if (g != 0) return;
    float wv = inv[wid];
    const size_t ob = (size_t)wid * STRIDE + cl * 8;
    float v[8];
    if constexpr (EPI == 0) {
#pragma unroll
        for (int t = 0; t < 8; ++t) v[t] = acc[t] * wv;
    } else {
        uint4 yv4 = *(const uint4*)(y + ob);
        const __half2* yp = (const __half2*)&yv4;
        float4 b0 = *(const float4*)(bias + cl * 8);
        float4 b1 = *(const float4*)(bias + cl * 8 + 4);
        float bb[8] = {b0.x, b0.y, b0.z, b0.w, b1.x, b1.y, b1.z, b1.w};
#pragma unroll
        for (int t = 0; t < 4; ++t) {
            float2 f = __half22float2(yp[t]);
            v[t * 2 + 0] = leaky(acc[t * 2 + 0] * wv + f.x + bb[t * 2 + 0]);
            v[t * 2 + 1] = leaky(acc[t * 2 + 1] * wv + f.y + bb[t * 2 + 1]);
        }
    }
    if constexpr (EPI == 3) {
        *(float4*)(outf + ob)     = make_float4(v[0], v[1], v[2], v[3]);
        *(float4*)(outf + ob + 4) = make_float4(v[4], v[5], v[6], v[7]);
    } else {
        *(ushort4*)(outh + ob)     = make_ushort4(f2h(v[0]), f2h(v[1]), f2h(v[2]), f2h(v[3]));
        *(ushort4*)(outh + ob + 4) = make_ushort4(f2h(v[4]), f2h(v[5]), f2h(v[6]), f2h(v[7]));
    }
}

// ---------------- fp16 MFMA GEMM: 128x128 tile, dbuf, COALESCED LDS-transpose epi --
// K-loop = R8/R10 (swapped mfma(fb,fa): acc holds C[row=..+fr][col=..+q*4+reg]).
// Epilogue: per wave, 4 passes x (stage 16 rows x 64 cols into private padded LDS,
// read back 16B/lane with 8 lanes covering one 128B row-run) -> global_store_dwordx4
// with fully-covered 64B lines. Tests the write-path line-traffic theory
// (WRITE_SIZE 56MB for 25.6MB useful => 2.2x partial-line overhead).
__global__ __launch_bounds__(256, 5) void k_gemm_f(
    int M, int nct,
    const u16* __restrict__ A1, const u16* __restrict__ B1, int K1,
    const u16* __restrict__ A2, const u16* __restrict__ B2, int K2,
    const float* __restrict__ bias, int act, int colsplit,
    u16* __restrict__ out1h, int n1, u16* __restrict__ out2h, int n2) {
    __shared__ u16 sh[16384];               // 32 KB: K-loop A/B dbuf; reused by epilogue
    u16* Ash0 = sh;                         // [2][4096]
    u16* Bsh0 = sh + 8192;                  // [2][4096]
    const int tid = threadIdx.x;
    const int lane = tid & 63;
    const int w = tid >> 6;
    const int wm = w & 1, wn = w >> 1;
    const int fr = lane & 15;
    const int q = lane >> 4;

    const int mT = (M + 127) >> 7;
    const int lin = blockIdx.x;
    const int grp = lin / (8 * nct);
    const int idx = lin - grp * (8 * nct);
    const int ct = idx >> 3;
    const int s8 = idx & 7;
    const int rowt = grp * 8 + s8;
    if (rowt >= mT) return;
    const int brow = rowt * 128;
    const int bcol = ct * 128;

    const int T1 = K1 >> 5, T = T1 + (K2 >> 5);

    const int c0 = (w * 2 + 0) * 64 + lane;
    const int c1 = (w * 2 + 1) * 64 + lane;
    const int r0 = c0 >> 2, g0 = (c0 & 3) ^ ((r0 >> 1) & 3);
    const int r1 = c1 >> 2, g1 = (c1 & 3) ^ ((r1 >> 1) & 3);
    int ar0 = brow + r0; if (ar0 >= M) ar0 = M - 1;
    int ar1 = brow + r1; if (ar1 >= M) ar1 = M - 1;
    const int br0 = bcol + r0, br1 = bcol + r1;
    const int ub0 = (w * 2 + 0) * 512;
    const int ub1 = (w * 2 + 1) * 512;

    auto stage = [&](int kt, int buf) {
        const u16 *A, *B; int K, k0;
        if (kt < T1) { A = A1; B = B1; K = K1; k0 = kt * 32; }
        else         { A = A2; B = B2; K = K2; k0 = (kt - T1) * 32; }
        async_load16(A + (size_t)ar0 * K + k0 + g0 * 8, &Ash0[buf * 4096 + ub0]);
        async_load16(A + (size_t)ar1 * K + k0 + g1 * 8, &Ash0[buf * 4096 + ub1]);
        async_load16(B + (size_t)br0 * K + k0 + g0 * 8, &Bsh0[buf * 4096 + ub0]);
        async_load16(B + (size_t)br1 * K + k0 + g1 * 8, &Bsh0[buf * 4096 + ub1]);
    };

    f32x4 acc[4][4] = {};

    // prologue: tile 0 into buf 0
    stage(0, 0);
    __syncthreads();               // vmcnt(0) drain + barrier

    int cur = 0;
    for (int kt = 0; kt < T; ++kt) {
        if (kt + 1 < T) stage(kt + 1, cur ^ 1);   // prefetch in flight under compute
        f16x8 fa[4], fb[4];
#pragma unroll
        for (int rt = 0; rt < 4; ++rt) {
            int row = wm * 64 + rt * 16 + fr;
            int ad = row * 32 + ((q ^ ((row >> 1) & 3)) * 8);
            fa[rt] = __builtin_bit_cast(f16x8, *(const uint4*)&Ash0[cur * 4096 + ad]);
        }
#pragma unroll
        for (int ctf = 0; ctf < 4; ++ctf) {
            int row = wn * 64 + ctf * 16 + fr;
            int ad = row * 32 + ((q ^ ((row >> 1) & 3)) * 8);
            fb[ctf] = __builtin_bit_cast(f16x8, *(const uint4*)&Bsh0[cur * 4096 + ad]);
        }
        // SWAPPED: value(reg r, lane) = C[row=fr-idx][col=q*4+r]
#pragma unroll
        for (int rt = 0; rt < 4; ++rt)
#pragma unroll
            for (int ctf = 0; ctf < 4; ++ctf)
                acc[rt][ctf] = __builtin_amdgcn_mfma_f32_16x16x32_f16(fb[ctf], fa[rt], acc[rt][ctf], 0, 0, 0);
        if (kt + 1 < T) __syncthreads();          // drain prefetch + protect buf reuse
        cur ^= 1;
    }

    // ---- coalesced epilogue ----
    __syncthreads();   // all waves done reading K-loop LDS before we overwrite it
    // block-uniform output routing (col tiles never straddle colsplit: 128 | 256)
    u16* outp; int nstr, cb;
    if (bcol < colsplit) { outp = out1h; nstr = n1; cb = bcol; }
    else                 { outp = out2h; nstr = n2; cb = bcol - colsplit; }
    // per-wave private region: 16 rows x 72 cols (pad) = 1152 u16 (2304 B, 16B-aligned)
    u16* ep = sh + w * 1152;
    const int rrd = lane >> 3;          // 0..7  (row within 8-row read group)
    const int chunk = lane & 7;         // 0..7  (16B chunk within 128B row-run)
#pragma unroll
    for (int rt = 0; rt < 4; ++rt) {
        // stage this rt-block (rows rt*16+fr, cols wn*64 + ctf*16+q*4 ..+3)
#pragma unroll
        for (int ctf = 0; ctf < 4; ++ctf) {
            int col = bcol + wn * 64 + ctf * 16 + q * 4;
            float4 b4 = bias ? *(const float4*)(bias + col) : make_float4(0.f, 0.f, 0.f, 0.f);
            float v0 = acc[rt][ctf][0] + b4.x;
            float v1 = acc[rt][ctf][1] + b4.y;
            float v2 = acc[rt][ctf][2] + b4.z;
            float v3 = acc[rt][ctf][3] + b4.w;
            if (act) { v0 = leaky(v0); v1 = leaky(v1); v2 = leaky(v2); v3 = leaky(v3); }
            *(ushort4*)&ep[fr * 72 + ctf * 16 + q * 4] =
                make_ushort4(f2h(v0), f2h(v1), f2h(v2), f2h(v3));
        }
        // read back coalesced: 8 lanes x 16B = one 128B row-run; 2 instrs cover 16 rows
#pragma unroll
        for (int i = 0; i < 2; ++i) {
            int rl = i * 8 + rrd;                       // row within rt-block
            uint4 vv = *(const uint4*)&ep[rl * 72 + chunk * 8];
            int row = brow + wm * 64 + rt * 16 + rl;
            if (row < M)
                *(uint4*)(outp + (size_t)row * nstr + cb + wn * 64 + chunk * 8) = vv;
        }
    }
}

// ---------------- fp16 MFMA GEMM: 128x64 tile, double-buffer, swapped epilogue -----
// Small-N variant for the layer-3 GEMM.
__global__ __launch_bounds__(256, 6) void k_gemm_s(
    int M, int nct,
    const u16* __restrict__ A1, const u16* __restrict__ B1, int K1,
    const float* __restrict__ bias, int act, int colsplit,
    u16* __restrict__ out1h, int n1, u16* __restrict__ out2h, int n2) {
    __shared__ u16 Ash[2][4096], Bsh[2][2048];
    const int tid = threadIdx.x;
    const int lane = tid & 63;
    const int w = tid >> 6;
    const int wm = w & 1, wn = w >> 1;
    const int fr = lane & 15;
    const int q = lane >> 4;

    const int mT = (M + 127) >> 7;
    const int lin = blockIdx.x;
    const int grp = lin / (8 * nct);
    const int idx = lin - grp * (8 * nct);
    const int ct = idx >> 3;
    const int s8 = idx & 7;
    const int rowt = grp * 8 + s8;
    if (rowt >= mT) return;
    const int brow = rowt * 128;
    const int bcol = ct * 64;

    const int T = K1 >> 5;

    const int sA0 = (w * 2 + 0) * 64 + lane;
    const int sA1 = (w * 2 + 1) * 64 + lane;
    const int rA0 = sA0 >> 2, gA0 = (sA0 & 3) ^ ((rA0 >> 1) & 3);
    const int rA1 = sA1 >> 2, gA1 = (sA1 & 3) ^ ((rA1 >> 1) & 3);
    int ar0 = brow + rA0; if (ar0 >= M) ar0 = M - 1;
    int ar1 = brow + rA1; if (ar1 >= M) ar1 = M - 1;
    const int sB = w * 64 + lane;
    const int rB = sB >> 2, gB = (sB & 3) ^ ((rB >> 1) & 3);
    const int br = bcol + rB;
    const int ubA0 = (w * 2 + 0) * 512;
    const int ubA1 = (w * 2 + 1) * 512;
    const int ubB  = w * 512;

    auto stage = [&](int kt, int buf) {
        int k0 = kt * 32;
        async_load16(A1 + (size_t)ar0 * K1 + k0 + gA0 * 8, &Ash[buf][ubA0]);
        async_load16(A1 + (size_t)ar1 * K1 + k0 + gA1 * 8, &Ash[buf][ubA1]);
        async_load16(B1 + (size_t)br  * K1 + k0 + gB  * 8, &Bsh[buf][ubB]);
    };

    f32x4 acc[4][2] = {};

    stage(0, 0);
    __syncthreads();

    int cur = 0;
    for (int kt = 0; kt < T; ++kt) {
        if (kt + 1 < T) stage(kt + 1, cur ^ 1);
        f16x8 fa[4], fb[2];
#pragma unroll
        for (int rt = 0; rt < 4; ++rt) {
            int row = wm * 64 + rt * 16 + fr;
            int ad = row * 32 + ((q ^ ((row >> 1) & 3)) * 8);
            fa[rt] = __builtin_bit_cast(f16x8, *(const uint4*)&Ash[cur][ad]);
        }
#pragma unroll
        for (int ctf = 0; ctf < 2; ++ctf) {
            int row = wn * 32 + ctf * 16 + fr;
            int ad = row * 32 + ((q ^ ((row >> 1) & 3)) * 8);
            fb[ctf] = __builtin_bit_cast(f16x8, *(const uint4*)&Bsh[cur][ad]);
        }
#pragma unroll
        for (int rt = 0; rt < 4; ++rt)
#pragma unroll
            for (int ctf = 0; ctf < 2; ++ctf)
                acc[rt][ctf] = __builtin_amdgcn_mfma_f32_16x16x32_f16(fb[ctf], fa[rt], acc[rt][ctf], 0, 0, 0);
        if (kt + 1 < T) __syncthreads();
        cur ^= 1;
    }

#pragma unroll
    for (int rt = 0; rt < 4; ++rt) {
        int row = brow + wm * 64 + rt * 16 + fr;
        if (row >= M) continue;
#pragma unroll
        for (int ctf = 0; ctf < 2; ++ctf) {
            int col0 = bcol + wn * 32 + ctf * 16 + q * 4;
            float4 b4 = bias ? *(const float4*)(bias + col0) : make_float4(0.f, 0.f, 0.f, 0.f);
            float v0 = acc[rt][ctf][0] + b4.x;
            float v1 = acc[rt][ctf][1] + b4.y;
            float v2 = acc[rt][ctf][2] + b4.z;
            float v3 = acc[rt][ctf][3] + b4.w;
            if (act) { v0 = leaky(v0); v1 = leaky(v1); v2 = leaky(v2); v3 = leaky(v3); }
            ushort4 pk = make_ushort4(f2h(v0), f2h(v1), f2h(v2), f2h(v3));
            if (col0 < colsplit) *(ushort4*)(out1h + (size_t)row * n1 + col0) = pk;
            else                 *(ushort4*)(out2h + (size_t)row * n2 + (col0 - colsplit)) = pk;
        }
    }
}

// ---------------- fused head: h3 -> pre_fc -> leaky(fc1) -> fc2 ------
__global__ __launch_bounds__(256) void k_head(const float* __restrict__ h3,
                                              const float* __restrict__ Wp, const float* __restrict__ bp,
                                              const float* __restrict__ Wf1, const float* __restrict__ bf1,
                                              const float* __restrict__ Wf2, const float* __restrict__ bf2,
                                              float* __restrict__ out) {
    __shared__ float sWp[64 * 32], sW1[32 * 32], sW2[32 * 2];
    __shared__ float sbp[32], sb1[32], sb2[2];
    int tid = threadIdx.x;
    for (int i = tid; i < 64 * 32; i += 256) sWp[i] = Wp[i];
    for (int i = tid; i < 32 * 32; i += 256) sW1[i] = Wf1[i];
    for (int i = tid; i < 64; i += 256) sW2[i] = Wf2[i];
    if (tid < 32) { sbp[tid] = bp[tid]; sb1[tid] = bf1[tid]; }
    if (tid < 2) sb2[tid] = bf2[tid];
    __syncthreads();
    int row = blockIdx.x * 256 + tid;
    if (row >= N_NODES) return;
    const float4* h4v = (const float4*)(h3 + (size_t)row * 64);
    float xr[64];
#pragma unroll
    for (int i = 0; i < 16; ++i) {
        float4 v = h4v[i];
        xr[i * 4 + 0] = v.x; xr[i * 4 + 1] = v.y;
        xr[i * 4 + 2] = v.z; xr[i * 4 + 3] = v.w;
    }
    float h4[32];
    for (int o = 0; o < 32; ++o) {
        float s = sbp[o];
#pragma unroll
        for (int i = 0; i < 64; ++i) s += xr[i] * sWp[i * 32 + o];
        h4[o] = s;
    }
    float h5[32];
    for (int o = 0; o < 32; ++o) {
        float s = sb1[o];
#pragma unroll
        for (int i = 0; i < 32; ++i) s += h4[i] * sW1[i * 32 + o];
        h5[o] = leaky(s);
    }
#pragma unroll
    for (int o = 0; o < 2; ++o) {
        float s = sb2[o];
#pragma unroll
        for (int i = 0; i < 32; ++i) s += h5[i] * sW2[i * 2 + o];
        out[(size_t)row * 2 + o] = s;
    }
}

// ---------------- launch ----------------
extern "C" void kernel_launch(void* const* d_in, const int* in_sizes, int n_in,
                              void* d_out, int out_size, void* d_ws, size_t ws_size,
                              hipStream_t stream) {
    const float* x   = (const float*)d_in[0];
    const int*   ei  = (const int*)d_in[1];
    const float* W1l = (const float*)d_in[5];
    const float* b1  = (const float*)d_in[6];
    const float* W1r = (const float*)d_in[7];
    const float* W2l = (const float*)d_in[8];
    const float* b2  = (const float*)d_in[9];
    const float* W2r = (const float*)d_in[10];
    const float* W3l = (const float*)d_in[11];
    const float* b3  = (const float*)d_in[12];
    const float* W3r = (const float*)d_in[13];
    const float* Wp  = (const float*)d_in[14];
    const float* bp  = (const float*)d_in[15];
    const float* Wf1 = (const float*)d_in[16];
    const float* bf1 = (const float*)d_in[17];
    const float* Wf2 = (const float*)d_in[18];
    const float* bf2 = (const float*)d_in[19];
    float* out = (float*)d_out;
    (void)in_sizes; (void)n_in; (void)out_size; (void)ws_size;

    const int* src = ei;
    const int* dst = ei + N_EDGES;

    char* base = (char*)d_ws;
    size_t off = 0;
    auto alloc = [&](size_t bytes) -> void* {
        void* r = base + off;
        off = (off + bytes + 255) & ~(size_t)255;
        return r;
    };
    const size_t NN = N_NODES;
    int*   cnt    = (int*)alloc(NN * 4);
    int*   offs   = (int*)alloc((NN + 1) * 4);      // padded CSR offsets
    float* inv    = (float*)alloc(NN * 4);
    int*   bsum   = (int*)alloc(64 * 4);
    int*   erank  = (int*)alloc((size_t)N_EDGES * 4);               // per-edge rank in dst
    int*   pssrc  = (int*)alloc((size_t)(N_EDGES + 8 * N_NODES) * 4);   // padded src list
    u16* w1lp = (u16*)alloc(128 * 512 * 2);
    u16* w1rp = (u16*)alloc(128 * 512 * 2);
    u16* w2cp = (u16*)alloc(512 * 512 * 2);
    u16* w3cp = (u16*)alloc(128 * 256 * 2);
    // gathered tables carry one extra zeroed pad row (index N_NODES)
    u16* xp  = (u16*)alloc((NN + 1) * 128 * 2);
    u16* axp = (u16*)alloc(NN * 128 * 2);
    u16* h1p = (u16*)alloc(NN * 512 * 2);
    u16* z2h = (u16*)alloc((NN + 1) * 256 * 2);
    u16* y2h = (u16*)alloc(NN * 256 * 2);
    u16* h2p = (u16*)alloc(NN * 256 * 2);
    u16* z3h = (u16*)alloc((NN + 1) * 64 * 2);
    u16* y3h = (u16*)alloc(NN * 64 * 2);
    float* h3f = (float*)alloc(NN * 64 * 4);

    // CSR + prep (pad-row zeroing folded into k_prep)
    hipMemsetAsync(cnt, 0, NN * 4, stream);
    k_prep<<<3125 + 6250 + 1664 + 2, 256, 0, stream>>>(dst, cnt, erank, x, xp,
        W1l, W1r, W2l, W2r, W3l, W3r, w1lp, w1rp, w2cp, w3cp, z2h, z3h);
    const int nb = (N_NODES + 1023) / 1024;   // 49
    k_scan1<<<nb, 1024, 0, stream>>>(cnt, offs, bsum);
    k_scan3<<<(N_NODES + 255) / 256, 256, 0, stream>>>(cnt, offs, inv, pssrc, bsum, nb);
    k_fill<<<(N_EDGES / 4 + 255) / 256, 256, 0, stream>>>(src, dst, erank, offs, pssrc);

    const int aggGrid = N_NODES / 4;                   // 12500 exact (4 waves/block)
    const int mT = (N_NODES + 127) / 128;              // 391
    const int grid4 = ((mT + 7) / 8) * 32;             // nct=4 (128-col tiles, N=512)
    const int grid2s = ((mT + 7) / 8) * 8 * 2;         // nct=2 (64-col tiles, N=128)

    // layer 1: aggX = mean-gather of xp (128 cols, full row per wave)
    k_agg<128, 0, 16, 4><<<aggGrid, 256, 0, stream>>>(
        xp, offs, pssrc, inv, nullptr, nullptr, axp, nullptr);
    k_gemm_f<<<grid4, 256, 0, stream>>>(N_NODES, 4,
        axp, w1lp, 128, xp, w1rp, 128, b1, 1, 512, h1p, 512, nullptr, 0);

    // layer 2: [z2|y2] = h1 @ [W2l|W2r] (fp16); h2 = leaky(mean z2 + y2 + b2) (fp16)
    k_gemm_f<<<grid4, 256, 0, stream>>>(N_NODES, 4,
        h1p, w2cp, 512, nullptr, nullptr, 0, nullptr, 0, 256, z2h, 256, y2h, 256);
    k_agg<256, 2, 32, 4><<<aggGrid, 256, 0, stream>>>(
        z2h, offs, pssrc, inv, y2h, b2, h2p, nullptr);

    // layer 3: [z3|y3] = h2 @ [W3l|W3r] (fp16); h3 = leaky(mean z3 + y3 + b3) (f32)
    k_gemm_s<<<grid2s, 256, 0, stream>>>(N_NODES, 2,
        h2p, w3cp, 256, nullptr, 0, 64, z3h, 64, y3h, 64);
    k_agg<64, 3, 8, 2><<<aggGrid, 256, 0, stream>>>(
        z3h, offs, pssrc, inv, y3h, b3, nullptr, h3f);

    // head: h3 -> pre_fc -> leaky(fc1) -> fc2
    k_head<<<(N_NODES + 255) / 256, 256, 0, stream>>>(h3f,
        Wp, bp, Wf1, bf1, Wf2, bf2, out);
}

// Round 12
// 387.744 us; speedup vs baseline: 1.3727x; 1.0169x over previous
//
#include <hip/hip_runtime.h>
#include <hip/hip_fp16.h>

#define N_NODES 50000
#define N_EDGES 800000
#define SLOPE 0.15f

typedef unsigned short u16;
typedef __attribute__((ext_vector_type(8))) _Float16 f16x8;
typedef __attribute__((ext_vector_type(2))) _Float16 h16x2;
typedef __attribute__((ext_vector_type(4))) float f32x4;

static __device__ __forceinline__ float leaky(float v) { return v > 0.f ? v : SLOPE * v; }

static __device__ __forceinline__ u16 f2h(float v) {
    return __builtin_bit_cast(u16, __float2half(v));
}

// acc += lo_half + hi_half of u (fp16 pair), f32 accumulate via v_dot2_f32_f16
static __device__ __forceinline__ float dot2acc(unsigned int u, float c) {
    h16x2 one = {(_Float16)1.0f, (_Float16)1.0f};
    return __builtin_amdgcn_fdot2(__builtin_bit_cast(h16x2, u), one, c, false);
}

// async global->LDS 16B: HW writes lane's data to (wave-uniform lds base) + lane*16
static __device__ __forceinline__ void async_load16(const u16* g, u16* l) {
    __builtin_amdgcn_global_load_lds(
        (const __attribute__((address_space(1))) unsigned int*)g,
        (__attribute__((address_space(3))) unsigned int*)l, 16, 0, 0);
}

// ---------------- merged prep: edge count+rank | x->fp16 | weight transpose | padzero
// block ranges: [0,3125) count+rank; [3125,9375) xconv; [9375,11039) wconv; [11039,11041) pad
__global__ void k_prep(const int* __restrict__ dst, int* __restrict__ cnt,
                       int* __restrict__ erank,
                       const float* __restrict__ x, u16* __restrict__ xp,
                       const float* __restrict__ W1l, const float* __restrict__ W1r,
                       const float* __restrict__ W2l, const float* __restrict__ W2r,
                       const float* __restrict__ W3l, const float* __restrict__ W3r,
                       u16* w1lp, u16* w1rp, u16* w2cp, u16* w3cp,
                       u16* z2h, u16* z3h) {
    int b = blockIdx.x, tid = threadIdx.x;
    if (b < 3125) {
        int e = b * 256 + tid;
        if (e < N_EDGES) erank[e] = atomicAdd(&cnt[dst[e]], 1);  // rank within dst node
        return;
    }
    b -= 3125;
    if (b < 6250) {
        int i = b * 256 + tid;
        if (i >= N_NODES * 32) return;
        float4 v = ((const float4*)x)[i];
        ((ushort4*)xp)[i] = make_ushort4(f2h(v.x), f2h(v.y), f2h(v.z), f2h(v.w));
        return;
    }
    b -= 6250;
    if (b >= 1664) {   // pad-row zeroing: xp row N (128), z2h row N (256), z3h row N (64)
        int i = (b - 1664) * 256 + tid;
        if (i < 128)      xp[(size_t)N_NODES * 128 + i] = 0;
        else if (i < 384) z2h[(size_t)N_NODES * 256 + (i - 128)] = 0;
        else if (i < 448) z3h[(size_t)N_NODES * 64 + (i - 384)] = 0;
        return;
    }
    const float* W; u16* op; int K, N;
    if (b < 256)       { W = W1l; op = w1lp; K = 128; N = 512; }
    else if (b < 512)  { W = W1r; op = w1rp; K = 128; N = 512; b -= 256; }
    else if (b < 1024) { W = W2l; op = w2cp; K = 512; N = 256; b -= 512; }
    else if (b < 1536) { W = W2r; op = w2cp + 256 * 512; K = 512; N = 256; b -= 1024; }
    else if (b < 1600) { W = W3l; op = w3cp; K = 256; N = 64; b -= 1536; }
    else               { W = W3r; op = w3cp + 64 * 256; K = 256; N = 64; b -= 1600; }
    int i = b * 256 + tid;
    if (i >= K * N) return;
    int k = i / N, n = i - k * N;
    op[(size_t)n * K + k] = f2h(W[i]);   // W^T [N][K] fp16
}

// multi-block scan over PADDED counts (pad each node to multiple of 8 slots)
__global__ __launch_bounds__(1024) void k_scan1(const int* __restrict__ cnt,
                                                int* __restrict__ offs,
                                                int* __restrict__ bsum) {
    __shared__ int wsum[16];
    int tid = threadIdx.x, lane = tid & 63, wv = tid >> 6;
    int i = blockIdx.x * 1024 + tid;
    int c = (i < N_NODES) ? cnt[i] : 0;
    int orig = (c + 7) & ~7;            // padded count (mult of 8)
    int v = orig;
#pragma unroll
    for (int d = 1; d < 64; d <<= 1) {
        int t = __shfl_up(v, d, 64);
        if (lane >= d) v += t;
    }
    if (lane == 63) wsum[wv] = v;
    __syncthreads();
    if (wv == 0) {
        int s = (lane < 16) ? wsum[lane] : 0;
#pragma unroll
        for (int d = 1; d < 16; d <<= 1) {
            int t = __shfl_up(s, d, 64);
            if (lane >= d) s += t;
        }
        if (lane < 16) wsum[lane] = s;
        if (lane == 15) bsum[blockIdx.x] = s;
    }
    __syncthreads();
    int wpre = (wv == 0) ? 0 : wsum[wv - 1];
    if (i < N_NODES) offs[i] = v + wpre - orig;
}

// stage 2+3 merged (padded offsets; offs[N_NODES]=total) + per-node pad-sentinel fill
__global__ void k_scan3(const int* __restrict__ cnt, int* __restrict__ offs,
                        float* __restrict__ inv, int* __restrict__ pssrc,
                        const int* __restrict__ bsum, int nb) {
    __shared__ int sb[64];
    int tid = threadIdx.x;
    if (tid < 64) {
        int v = (tid < nb) ? bsum[tid] : 0;
        int s = v;
#pragma unroll
        for (int d = 1; d < 64; d <<= 1) {
            int t = __shfl_up(s, d, 64);
            if (tid >= d) s += t;
        }
        sb[tid] = s - v;
        if (blockIdx.x == 0 && tid == nb - 1) offs[N_NODES] = s;  // total padded
    }
    __syncthreads();
    int i = blockIdx.x * 256 + tid;
    if (i >= N_NODES) return;
    int c = cnt[i];
    int o = offs[i] + sb[i >> 10];
    offs[i] = o;
    inv[i] = 1.0f / (float)(c > 1 ? c : 1);
    int cp = (c + 7) & ~7;
    for (int j = c; j < cp; ++j) pssrc[o + j] = N_NODES;   // zero pad row sentinel
}

// atomic-free fill: pssrc[offs[dst]+rank] = src ; 4 edges/thread, fire-and-forget
__global__ void k_fill(const int* __restrict__ src, const int* __restrict__ dst,
                       const int* __restrict__ erank, const int* __restrict__ poffs,
                       int* __restrict__ pssrc) {
    int t = blockIdx.x * 256 + threadIdx.x;
    int e = t * 4;
    if (e + 3 >= N_EDGES) {
        for (; e < N_EDGES; ++e) pssrc[poffs[dst[e]] + erank[e]] = src[e];
        return;
    }
    int4 d4 = *(const int4*)&dst[e];
    int4 s4 = *(const int4*)&src[e];
    int4 r4 = *(const int4*)&erank[e];
    int p0 = poffs[d4.x] + r4.x;
    int p1 = poffs[d4.y] + r4.y;
    int p2 = poffs[d4.z] + r4.z;
    int p3 = poffs[d4.w] + r4.w;
    pssrc[p0] = s4.x;
    pssrc[p1] = s4.y;
    pssrc[p2] = s4.z;
    pssrc[p3] = s4.w;
}

// ---------------- padded-CSR mean aggregation, full-row waves --------------------
// One wave per node, LPE lanes per edge (LPE*8 = STRIDE cols), G=64/LPE edge groups,
// U consecutive edges unrolled per lane (U mult of 4 -> int4 idx loads; else int2).
// CSR padded to 8; chunk starts are U-aligned so the e<end guard covers remainders.
// Deep U = more gathers in flight per wave (L3-latency hiding, m11 finding).
// EPI: 0 = mean -> fp16 outh; 2 = leaky(mean+y+bias) -> fp16 outh; 3 = -> f32 outf
template <int STRIDE, int EPI, int LPE, int U>
__global__ __launch_bounds__(256) void k_agg(const u16* __restrict__ tbl,
                                             const int* __restrict__ poffs,
                                             const int* __restrict__ pssrc,
                                             const float* __restrict__ inv,
                                             const u16* __restrict__ y,
                                             const float* __restrict__ bias,
                                             u16* __restrict__ outh,
                                             float* __restrict__ outf) {
    constexpr int G = 64 / LPE;
    int wid = (blockIdx.x * 256 + threadIdx.x) >> 6;
    if (wid >= N_NODES) return;
    int lane = threadIdx.x & 63;
    int g = lane / LPE;
    int cl = lane % LPE;
    int beg = poffs[wid], end = poffs[wid + 1];
    const u16* colbase = tbl + cl * 8;
    float acc[8] = {};
    for (int e = beg + g * U; e < end; e += G * U) {
        int idx[U];
        if constexpr (U % 4 == 0) {
#pragma unroll
            for (int j = 0; j < U / 4; ++j) {
                int4 t4 = *(const int4*)&pssrc[e + j * 4];
                idx[j * 4 + 0] = t4.x; idx[j * 4 + 1] = t4.y;
                idx[j * 4 + 2] = t4.z; idx[j * 4 + 3] = t4.w;
            }
        } else {
            int2 t2 = *(const int2*)&pssrc[e];
            idx[0] = t2.x; idx[1] = t2.y;
        }
        uint4 rv[U];
#pragma unroll
        for (int j = 0; j < U; ++j)
            rv[j] = *(const uint4*)(colbase + (size_t)idx[j] * STRIDE);
#pragma unroll
        for (int p = 0; p < U / 2; ++p) {
            const unsigned int* a = (const unsigned int*)&rv[2 * p];
            const unsigned int* b = (const unsigned int*)&rv[2 * p + 1];
#pragma unroll
            for (int t = 0; t < 4; ++t) {
                // lo = (a.col2t, b.col2t), hi = (a.col2t+1, b.col2t+1)
                unsigned int lo = __builtin_amdgcn_perm(b[t], a[t], 0x05040100u);
                unsigned int hi = __builtin_amdgcn_perm(b[t], a[t], 0x07060302u);
                acc[2 * t + 0] = dot2acc(lo, acc[2 * t + 0]);
                acc[2 * t + 1] = dot2acc(hi, acc[2 * t + 1]);
            }
        }
    }
    // reduce across the G edge groups (group stride = LPE lanes)
#pragma unroll
    for (int m = LPE; m < 64; m <<= 1)
#pragma unroll
        for (int t = 0; t < 8; ++t) acc[t] += __shfl_xor(acc[t], m, 64);
    if (g != 0) return;
    float wv = inv[wid];
    const size_t ob = (size_t)wid * STRIDE + cl * 8;
    float v[8];
    if constexpr (EPI == 0) {
#pragma unroll
        for (int t = 0; t < 8; ++t) v[t] = acc[t] * wv;
    } else {
        uint4 yv4 = *(const uint4*)(y + ob);
        const __half2* yp = (const __half2*)&yv4;
        float4 b0 = *(const float4*)(bias + cl * 8);
        float4 b1 = *(const float4*)(bias + cl * 8 + 4);
        float bb[8] = {b0.x, b0.y, b0.z, b0.w, b1.x, b1.y, b1.z, b1.w};
#pragma unroll
        for (int t = 0; t < 4; ++t) {
            float2 f = __half22float2(yp[t]);
            v[t * 2 + 0] = leaky(acc[t * 2 + 0] * wv + f.x + bb[t * 2 + 0]);
            v[t * 2 + 1] = leaky(acc[t * 2 + 1] * wv + f.y + bb[t * 2 + 1]);
        }
    }
    if constexpr (EPI == 3) {
        *(float4*)(outf + ob)     = make_float4(v[0], v[1], v[2], v[3]);
        *(float4*)(outf + ob + 4) = make_float4(v[4], v[5], v[6], v[7]);
    } else {
        *(ushort4*)(outh + ob)     = make_ushort4(f2h(v[0]), f2h(v[1]), f2h(v[2]), f2h(v[3]));
        *(ushort4*)(outh + ob + 4) = make_ushort4(f2h(v[4]), f2h(v[5]), f2h(v[6]), f2h(v[7]));
    }
}

// ---------------- fp16 MFMA GEMM: 128x128 tile, dbuf, COALESCED LDS-transpose epi --
// K-loop = R8/R10 (swapped mfma(fb,fa): acc holds C[row=..+fr][col=..+q*4+reg]).
// Epilogue: per wave, 4 passes x (stage 16 rows x 64 cols into private padded LDS,
// read back 16B/lane with 8 lanes covering one 128B row-run) -> global_store_dwordx4
// with fully-covered 64B lines. [R11: validated — WRITE-path was the GEMM plateau]
__global__ __launch_bounds__(256, 5) void k_gemm_f(
    int M, int nct,
    const u16* __restrict__ A1, const u16* __restrict__ B1, int K1,
    const u16* __restrict__ A2, const u16* __restrict__ B2, int K2,
    const float* __restrict__ bias, int act, int colsplit,
    u16* __restrict__ out1h, int n1, u16* __restrict__ out2h, int n2) {
    __shared__ u16 sh[16384];               // 32 KB: K-loop A/B dbuf; reused by epilogue
    u16* Ash0 = sh;                         // [2][4096]
    u16* Bsh0 = sh + 8192;                  // [2][4096]
    const int tid = threadIdx.x;
    const int lane = tid & 63;
    const int w = tid >> 6;
    const int wm = w & 1, wn = w >> 1;
    const int fr = lane & 15;
    const int q = lane >> 4;

    const int mT = (M + 127) >> 7;
    const int lin = blockIdx.x;
    const int grp = lin / (8 * nct);
    const int idx = lin - grp * (8 * nct);
    const int ct = idx >> 3;
    const int s8 = idx & 7;
    const int rowt = grp * 8 + s8;
    if (rowt >= mT) return;
    const int brow = rowt * 128;
    const int bcol = ct * 128;

    const int T1 = K1 >> 5, T = T1 + (K2 >> 5);

    const int c0 = (w * 2 + 0) * 64 + lane;
    const int c1 = (w * 2 + 1) * 64 + lane;
    const int r0 = c0 >> 2, g0 = (c0 & 3) ^ ((r0 >> 1) & 3);
    const int r1 = c1 >> 2, g1 = (c1 & 3) ^ ((r1 >> 1) & 3);
    int ar0 = brow + r0; if (ar0 >= M) ar0 = M - 1;
    int ar1 = brow + r1; if (ar1 >= M) ar1 = M - 1;
    const int br0 = bcol + r0, br1 = bcol + r1;
    const int ub0 = (w * 2 + 0) * 512;
    const int ub1 = (w * 2 + 1) * 512;

    auto stage = [&](int kt, int buf) {
        const u16 *A, *B; int K, k0;
        if (kt < T1) { A = A1; B = B1; K = K1; k0 = kt * 32; }
        else         { A = A2; B = B2; K = K2; k0 = (kt - T1) * 32; }
        async_load16(A + (size_t)ar0 * K + k0 + g0 * 8, &Ash0[buf * 4096 + ub0]);
        async_load16(A + (size_t)ar1 * K + k0 + g1 * 8, &Ash0[buf * 4096 + ub1]);
        async_load16(B + (size_t)br0 * K + k0 + g0 * 8, &Bsh0[buf * 4096 + ub0]);
        async_load16(B + (size_t)br1 * K + k0 + g1 * 8, &Bsh0[buf * 4096 + ub1]);
    };

    f32x4 acc[4][4] = {};

    // prologue: tile 0 into buf 0
    stage(0, 0);
    __syncthreads();               // vmcnt(0) drain + barrier

    int cur = 0;
    for (int kt = 0; kt < T; ++kt) {
        if (kt + 1 < T) stage(kt + 1, cur ^ 1);   // prefetch in flight under compute
        f16x8 fa[4], fb[4];
#pragma unroll
        for (int rt = 0; rt < 4; ++rt) {
            int row = wm * 64 + rt * 16 + fr;
            int ad = row * 32 + ((q ^ ((row >> 1) & 3)) * 8);
            fa[rt] = __builtin_bit_cast(f16x8, *(const uint4*)&Ash0[cur * 4096 + ad]);
        }
#pragma unroll
        for (int ctf = 0; ctf < 4; ++ctf) {
            int row = wn * 64 + ctf * 16 + fr;
            int ad = row * 32 + ((q ^ ((row >> 1) & 3)) * 8);
            fb[ctf] = __builtin_bit_cast(f16x8, *(const uint4*)&Bsh0[cur * 4096 + ad]);
        }
        // SWAPPED: value(reg r, lane) = C[row=fr-idx][col=q*4+r]
#pragma unroll
        for (int rt = 0; rt < 4; ++rt)
#pragma unroll
            for (int ctf = 0; ctf < 4; ++ctf)
                acc[rt][ctf] = __builtin_amdgcn_mfma_f32_16x16x32_f16(fb[ctf], fa[rt], acc[rt][ctf], 0, 0, 0);
        if (kt + 1 < T) __syncthreads();          // drain prefetch + protect buf reuse
        cur ^= 1;
    }

    // ---- coalesced epilogue ----
    __syncthreads();   // all waves done reading K-loop LDS before we overwrite it
    // block-uniform output routing (col tiles never straddle colsplit: 128 | 256)
    u16* outp; int nstr, cb;
    if (bcol < colsplit) { outp = out1h; nstr = n1; cb = bcol; }
    else                 { outp = out2h; nstr = n2; cb = bcol - colsplit; }
    // per-wave private region: 16 rows x 72 cols (pad) = 1152 u16 (2304 B, 16B-aligned)
    u16* ep = sh + w * 1152;
    const int rrd = lane >> 3;          // 0..7  (row within 8-row read group)
    const int chunk = lane & 7;         // 0..7  (16B chunk within 128B row-run)
#pragma unroll
    for (int rt = 0; rt < 4; ++rt) {
        // stage this rt-block (rows rt*16+fr, cols wn*64 + ctf*16+q*4 ..+3)
#pragma unroll
        for (int ctf = 0; ctf < 4; ++ctf) {
            int col = bcol + wn * 64 + ctf * 16 + q * 4;
            float4 b4 = bias ? *(const float4*)(bias + col) : make_float4(0.f, 0.f, 0.f, 0.f);
            float v0 = acc[rt][ctf][0] + b4.x;
            float v1 = acc[rt][ctf][1] + b4.y;
            float v2 = acc[rt][ctf][2] + b4.z;
            float v3 = acc[rt][ctf][3] + b4.w;
            if (act) { v0 = leaky(v0); v1 = leaky(v1); v2 = leaky(v2); v3 = leaky(v3); }
            *(ushort4*)&ep[fr * 72 + ctf * 16 + q * 4] =
                make_ushort4(f2h(v0), f2h(v1), f2h(v2), f2h(v3));
        }
        // read back coalesced: 8 lanes x 16B = one 128B row-run; 2 instrs cover 16 rows
#pragma unroll
        for (int i = 0; i < 2; ++i) {
            int rl = i * 8 + rrd;                       // row within rt-block
            uint4 vv = *(const uint4*)&ep[rl * 72 + chunk * 8];
            int row = brow + wm * 64 + rt * 16 + rl;
            if (row < M)
                *(uint4*)(outp + (size_t)row * nstr + cb + wn * 64 + chunk * 8) = vv;
        }
    }
}

// ---------------- fp16 MFMA GEMM: 128x64 tile, double-buffer, swapped epilogue -----
// Small-N variant for the layer-3 GEMM.
__global__ __launch_bounds__(256, 6) void k_gemm_s(
    int M, int nct,
    const u16* __restrict__ A1, const u16* __restrict__ B1, int K1,
    const float* __restrict__ bias, int act, int colsplit,
    u16* __restrict__ out1h, int n1, u16* __restrict__ out2h, int n2) {
    __shared__ u16 Ash[2][4096], Bsh[2][2048];
    const int tid = threadIdx.x;
    const int lane = tid & 63;
    const int w = tid >> 6;
    const int wm = w & 1, wn = w >> 1;
    const int fr = lane & 15;
    const int q = lane >> 4;

    const int mT = (M + 127) >> 7;
    const int lin = blockIdx.x;
    const int grp = lin / (8 * nct);
    const int idx = lin - grp * (8 * nct);
    const int ct = idx >> 3;
    const int s8 = idx & 7;
    const int rowt = grp * 8 + s8;
    if (rowt >= mT) return;
    const int brow = rowt * 128;
    const int bcol = ct * 64;

    const int T = K1 >> 5;

    const int sA0 = (w * 2 + 0) * 64 + lane;
    const int sA1 = (w * 2 + 1) * 64 + lane;
    const int rA0 = sA0 >> 2, gA0 = (sA0 & 3) ^ ((rA0 >> 1) & 3);
    const int rA1 = sA1 >> 2, gA1 = (sA1 & 3) ^ ((rA1 >> 1) & 3);
    int ar0 = brow + rA0; if (ar0 >= M) ar0 = M - 1;
    int ar1 = brow + rA1; if (ar1 >= M) ar1 = M - 1;
    const int sB = w * 64 + lane;
    const int rB = sB >> 2, gB = (sB & 3) ^ ((rB >> 1) & 3);
    const int br = bcol + rB;
    const int ubA0 = (w * 2 + 0) * 512;
    const int ubA1 = (w * 2 + 1) * 512;
    const int ubB  = w * 512;

    auto stage = [&](int kt, int buf) {
        int k0 = kt * 32;
        async_load16(A1 + (size_t)ar0 * K1 + k0 + gA0 * 8, &Ash[buf][ubA0]);
        async_load16(A1 + (size_t)ar1 * K1 + k0 + gA1 * 8, &Ash[buf][ubA1]);
        async_load16(B1 + (size_t)br  * K1 + k0 + gB  * 8, &Bsh[buf][ubB]);
    };

    f32x4 acc[4][2] = {};

    stage(0, 0);
    __syncthreads();

    int cur = 0;
    for (int kt = 0; kt < T; ++kt) {
        if (kt + 1 < T) stage(kt + 1, cur ^ 1);
        f16x8 fa[4], fb[2];
#pragma unroll
        for (int rt = 0; rt < 4; ++rt) {
            int row = wm * 64 + rt * 16 + fr;
            int ad = row * 32 + ((q ^ ((row >> 1) & 3)) * 8);
            fa[rt] = __builtin_bit_cast(f16x8, *(const uint4*)&Ash[cur][ad]);
        }
#pragma unroll
        for (int ctf = 0; ctf < 2; ++ctf) {
            int row = wn * 32 + ctf * 16 + fr;
            int ad = row * 32 + ((q ^ ((row >> 1) & 3)) * 8);
            fb[ctf] = __builtin_bit_cast(f16x8, *(const uint4*)&Bsh[cur][ad]);
        }
#pragma unroll
        for (int rt = 0; rt < 4; ++rt)
#pragma unroll
            for (int ctf = 0; ctf < 2; ++ctf)
                acc[rt][ctf] = __builtin_amdgcn_mfma_f32_16x16x32_f16(fb[ctf], fa[rt], acc[rt][ctf], 0, 0, 0);
        if (kt + 1 < T) __syncthreads();
        cur ^= 1;
    }

#pragma unroll
    for (int rt = 0; rt < 4; ++rt) {
        int row = brow + wm * 64 + rt * 16 + fr;
        if (row >= M) continue;
#pragma unroll
        for (int ctf = 0; ctf < 2; ++ctf) {
            int col0 = bcol + wn * 32 + ctf * 16 + q * 4;
            float4 b4 = bias ? *(const float4*)(bias + col0) : make_float4(0.f, 0.f, 0.f, 0.f);
            float v0 = acc[rt][ctf][0] + b4.x;
            float v1 = acc[rt][ctf][1] + b4.y;
            float v2 = acc[rt][ctf][2] + b4.z;
            float v3 = acc[rt][ctf][3] + b4.w;
            if (act) { v0 = leaky(v0); v1 = leaky(v1); v2 = leaky(v2); v3 = leaky(v3); }
            ushort4 pk = make_ushort4(f2h(v0), f2h(v1), f2h(v2), f2h(v3));
            if (col0 < colsplit) *(ushort4*)(out1h + (size_t)row * n1 + col0) = pk;
            else                 *(ushort4*)(out2h + (size_t)row * n2 + (col0 - colsplit)) = pk;
        }
    }
}

// ---------------- fused head: h3 -> pre_fc -> leaky(fc1) -> fc2 ------
__global__ __launch_bounds__(256) void k_head(const float* __restrict__ h3,
                                              const float* __restrict__ Wp, const float* __restrict__ bp,
                                              const float* __restrict__ Wf1, const float* __restrict__ bf1,
                                              const float* __restrict__ Wf2, const float* __restrict__ bf2,
                                              float* __restrict__ out) {
    __shared__ float sWp[64 * 32], sW1[32 * 32], sW2[32 * 2];
    __shared__ float sbp[32], sb1[32], sb2[2];
    int tid = threadIdx.x;
    for (int i = tid; i < 64 * 32; i += 256) sWp[i] = Wp[i];
    for (int i = tid; i < 32 * 32; i += 256) sW1[i] = Wf1[i];
    for (int i = tid; i < 64; i += 256) sW2[i] = Wf2[i];
    if (tid < 32) { sbp[tid] = bp[tid]; sb1[tid] = bf1[tid]; }
    if (tid < 2) sb2[tid] = bf2[tid];
    __syncthreads();
    int row = blockIdx.x * 256 + tid;
    if (row >= N_NODES) return;
    const float4* h4v = (const float4*)(h3 + (size_t)row * 64);
    float xr[64];
#pragma unroll
    for (int i = 0; i < 16; ++i) {
        float4 v = h4v[i];
        xr[i * 4 + 0] = v.x; xr[i * 4 + 1] = v.y;
        xr[i * 4 + 2] = v.z; xr[i * 4 + 3] = v.w;
    }
    float h4[32];
    for (int o = 0; o < 32; ++o) {
        float s = sbp[o];
#pragma unroll
        for (int i = 0; i < 64; ++i) s += xr[i] * sWp[i * 32 + o];
        h4[o] = s;
    }
    float h5[32];
    for (int o = 0; o < 32; ++o) {
        float s = sb1[o];
#pragma unroll
        for (int i = 0; i < 32; ++i) s += h4[i] * sW1[i * 32 + o];
        h5[o] = leaky(s);
    }
#pragma unroll
    for (int o = 0; o < 2; ++o) {
        float s = sb2[o];
#pragma unroll
        for (int i = 0; i < 32; ++i) s += h5[i] * sW2[i * 2 + o];
        out[(size_t)row * 2 + o] = s;
    }
}

// ---------------- launch ----------------
extern "C" void kernel_launch(void* const* d_in, const int* in_sizes, int n_in,
                              void* d_out, int out_size, void* d_ws, size_t ws_size,
                              hipStream_t stream) {
    const float* x   = (const float*)d_in[0];
    const int*   ei  = (const int*)d_in[1];
    const float* W1l = (const float*)d_in[5];
    const float* b1  = (const float*)d_in[6];
    const float* W1r = (const float*)d_in[7];
    const float* W2l = (const float*)d_in[8];
    const float* b2  = (const float*)d_in[9];
    const float* W2r = (const float*)d_in[10];
    const float* W3l = (const float*)d_in[11];
    const float* b3  = (const float*)d_in[12];
    const float* W3r = (const float*)d_in[13];
    const float* Wp  = (const float*)d_in[14];
    const float* bp  = (const float*)d_in[15];
    const float* Wf1 = (const float*)d_in[16];
    const float* bf1 = (const float*)d_in[17];
    const float* Wf2 = (const float*)d_in[18];
    const float* bf2 = (const float*)d_in[19];
    float* out = (float*)d_out;
    (void)in_sizes; (void)n_in; (void)out_size; (void)ws_size;

    const int* src = ei;
    const int* dst = ei + N_EDGES;

    char* base = (char*)d_ws;
    size_t off = 0;
    auto alloc = [&](size_t bytes) -> void* {
        void* r = base + off;
        off = (off + bytes + 255) & ~(size_t)255;
        return r;
    };
    const size_t NN = N_NODES;
    int*   cnt    = (int*)alloc(NN * 4);
    int*   offs   = (int*)alloc((NN + 1) * 4);      // padded CSR offsets
    float* inv    = (float*)alloc(NN * 4);
    int*   bsum   = (int*)alloc(64 * 4);
    int*   erank  = (int*)alloc((size_t)N_EDGES * 4);               // per-edge rank in dst
    int*   pssrc  = (int*)alloc((size_t)(N_EDGES + 8 * N_NODES) * 4);   // padded src list
    u16* w1lp = (u16*)alloc(128 * 512 * 2);
    u16* w1rp = (u16*)alloc(128 * 512 * 2);
    u16* w2cp = (u16*)alloc(512 * 512 * 2);
    u16* w3cp = (u16*)alloc(128 * 256 * 2);
    // gathered tables carry one extra zeroed pad row (index N_NODES)
    u16* xp  = (u16*)alloc((NN + 1) * 128 * 2);
    u16* axp = (u16*)alloc(NN * 128 * 2);
    u16* h1p = (u16*)alloc(NN * 512 * 2);
    u16* z2h = (u16*)alloc((NN + 1) * 256 * 2);
    u16* y2h = (u16*)alloc(NN * 256 * 2);
    u16* h2p = (u16*)alloc(NN * 256 * 2);
    u16* z3h = (u16*)alloc((NN + 1) * 64 * 2);
    u16* y3h = (u16*)alloc(NN * 64 * 2);
    float* h3f = (float*)alloc(NN * 64 * 4);

    // CSR + prep (pad-row zeroing folded into k_prep)
    hipMemsetAsync(cnt, 0, NN * 4, stream);
    k_prep<<<3125 + 6250 + 1664 + 2, 256, 0, stream>>>(dst, cnt, erank, x, xp,
        W1l, W1r, W2l, W2r, W3l, W3r, w1lp, w1rp, w2cp, w3cp, z2h, z3h);
    const int nb = (N_NODES + 1023) / 1024;   // 49
    k_scan1<<<nb, 1024, 0, stream>>>(cnt, offs, bsum);
    k_scan3<<<(N_NODES + 255) / 256, 256, 0, stream>>>(cnt, offs, inv, pssrc, bsum, nb);
    k_fill<<<(N_EDGES / 4 + 255) / 256, 256, 0, stream>>>(src, dst, erank, offs, pssrc);

    const int aggGrid = N_NODES / 4;                   // 12500 exact (4 waves/block)
    const int mT = (N_NODES + 127) / 128;              // 391
    const int grid4 = ((mT + 7) / 8) * 32;             // nct=4 (128-col tiles, N=512)
    const int grid2s = ((mT + 7) / 8) * 8 * 2;         // nct=2 (64-col tiles, N=128)

    // layer 1: aggX = mean-gather of xp (128 cols, full row per wave; U=8 deep volley)
    k_agg<128, 0, 16, 8><<<aggGrid, 256, 0, stream>>>(
        xp, offs, pssrc, inv, nullptr, nullptr, axp, nullptr);
    k_gemm_f<<<grid4, 256, 0, stream>>>(N_NODES, 4,
        axp, w1lp, 128, xp, w1rp, 128, b1, 1, 512, h1p, 512, nullptr, 0);

    // layer 2: [z2|y2] = h1 @ [W2l|W2r] (fp16); h2 = leaky(mean z2 + y2 + b2) (fp16)
    k_gemm_f<<<grid4, 256, 0, stream>>>(N_NODES, 4,
        h1p, w2cp, 512, nullptr, nullptr, 0, nullptr, 0, 256, z2h, 256, y2h, 256);
    k_agg<256, 2, 32, 8><<<aggGrid, 256, 0, stream>>>(
        z2h, offs, pssrc, inv, y2h, b2, h2p, nullptr);

    // layer 3: [z3|y3] = h2 @ [W3l|W3r] (fp16); h3 = leaky(mean z3 + y3 + b3) (f32)
    k_gemm_s<<<grid2s, 256, 0, stream>>>(N_NODES, 2,
        h2p, w3cp, 256, nullptr, 0, 64, z3h, 64, y3h, 64);
    k_agg<64, 3, 8, 4><<<aggGrid, 256, 0, stream>>>(
        z3h, offs, pssrc, inv, y3h, b3, nullptr, h3f);

    // head: h3 -> pre_fc -> leaky(fc1) -> fc2
    k_head<<<(N_NODES + 255) / 256, 256, 0, stream>>>(h3f,
        Wp, bp, Wf1, bf1, Wf2, bf2, out);
}